// Round 16
// baseline (141.100 us; speedup 1.0000x reference)
//
#include <hip/hip_runtime.h>

#define SQ 4096      // sequence length = 64*64
#define CCH 256      // channels
#define NH 8         // heads
#define HD 32        // head dim
#define LN_EPS 1e-5f
#define NSPLIT 4     // kv splits per head
#define VROWS 48     // V^T rows per head: 32 data + 16 pad (row32=ones, rest 0)

typedef __bf16 bf16x8 __attribute__((ext_vector_type(8)));
typedef float f32x4 __attribute__((ext_vector_type(4)));
typedef short s16x4 __attribute__((ext_vector_type(4)));
using bf16 = __bf16;

#if defined(__has_builtin)
#if __has_builtin(__builtin_amdgcn_mfma_f32_16x16x16bf16_1k)
#define HAVE_MFMA16 1
#else
#define HAVE_MFMA16 0
#endif
#else
#define HAVE_MFMA16 0
#endif

// Raw hardware 2^x (exp2f lowers to a ~20-VALU OCML guarded sequence;
// inputs here are bounded so the fixups are dead weight).
__device__ __forceinline__ float fast_exp2(float x) {
#if defined(__has_builtin)
#if __has_builtin(__builtin_amdgcn_exp2f)
    return __builtin_amdgcn_exp2f(x);
#else
    float r;
    asm("v_exp_f32 %0, %1" : "=v"(r) : "v"(x));
    return r;
#endif
#else
    float r;
    asm("v_exp_f32 %0, %1" : "=v"(r) : "v"(x));
    return r;
#endif
}

// ---------------------------------------------------------------------------
// Tile transpose + fp32->bf16 convert: src [R][Ccol] f32 -> dst [Ccol][R] bf16
// ---------------------------------------------------------------------------
__device__ __forceinline__ void tile_tc(const float* __restrict__ src, bf16* __restrict__ dst,
                                        int R, int Ccol, int ti, int tj) {
    __shared__ float t[32][33];
    const int tx = threadIdx.x & 31;
    const int ty = threadIdx.x >> 5;   // 0..7
    const int i0 = ti * 32, j0 = tj * 32;
    #pragma unroll
    for (int i = 0; i < 32; i += 8)
        t[ty + i][tx] = src[(size_t)(i0 + ty + i) * Ccol + j0 + tx];
    __syncthreads();
    #pragma unroll
    for (int i = 0; i < 32; i += 8)
        dst[(size_t)(j0 + ty + i) * R + i0 + tx] = (bf16)t[tx][ty + i];
}

// ---------------------------------------------------------------------------
// ALL conversions in one launch (2880 blocks).
// ---------------------------------------------------------------------------
__global__ __launch_bounds__(256)
void cvt_all(const float* __restrict__ x, const float* __restrict__ y,
             bf16* __restrict__ xT, bf16* __restrict__ yT,
             const float* Wq, const float* Wk, const float* Wv, const float* Wo,
             const float* W1, const float* W2,
             bf16* WqT, bf16* WkT, bf16* WvT, bf16* WoT, bf16* W1T, bf16* W2T,
             bf16* vTb) {
    const int id = blockIdx.x;
    if (id < 2048) {
        const int z = id >> 10;
        const int t = id & 1023;
        const float* s = z ? y : x;
        bf16* d = z ? yT : xT;
        tile_tc(s, d, CCH, SQ, t >> 7, t & 127);
        return;
    }
    const int wid = id - 2048;
    if (wid < 256) {
        const int w = wid >> 6, local = wid & 63;
        const float* s = (w == 0) ? Wq : (w == 1) ? Wk : (w == 2) ? Wv : Wo;
        bf16* d = (w == 0) ? WqT : (w == 1) ? WkT : (w == 2) ? WvT : WoT;
        tile_tc(s, d, 256, 256, local >> 3, local & 7);
    } else if (wid < 512) {
        const int local = wid - 256;
        tile_tc(W1, W1T, 256, 1024, local >> 5, local & 31);
    } else if (wid < 768) {
        const int local = wid - 512;
        tile_tc(W2, W2T, 1024, 256, local >> 3, local & 7);
    } else {
        // init vT pad rows: per head rows 32..47 -> row 32 = 1.0, rest 0
        const int local = wid - 768;         // 0..63
        #pragma unroll
        for (int rr = 0; rr < 2; ++rr) {
            const int pr = local * 2 + rr;   // 0..127
            const int hh = pr >> 4, j = pr & 15;
            const bf16 val = (bf16)((j == 0) ? 1.0f : 0.0f);
            bf16x8 v8;
            #pragma unroll
            for (int e = 0; e < 8; ++e) v8[e] = val;
            bf16* dst = vTb + ((size_t)hh * VROWS + 32 + j) * SQ + threadIdx.x * 16;
            *reinterpret_cast<bf16x8*>(dst) = v8;
            *reinterpret_cast<bf16x8*>(dst + 8) = v8;
        }
    }
}

// ---------------------------------------------------------------------------
// 4-wave MFMA GEMM: 64x64 tile, wave -> 32x32, reg fragments.
// OUT_MODE: 0 = f32; 2 = bf16.
// ---------------------------------------------------------------------------
template <int K, int OUT_MODE, bool RELU>
__global__ __launch_bounds__(256)
void gemm_mfma(const bf16* __restrict__ A, const bf16* __restrict__ BT,
               const float* __restrict__ bias, float* __restrict__ Cf,
               bf16* __restrict__ Cb, int N) {
    const int tid = threadIdx.x;
    const int w = tid >> 6, l = tid & 63;
    const int l15 = l & 15, lg = l >> 4;
    const int m0 = blockIdx.x * 64 + (w >> 1) * 32;
    const int n0 = blockIdx.y * 64 + (w & 1) * 32;

    f32x4 acc[2][2] = {};
    const bf16* a0 = &A[(size_t)(m0 + l15) * K + lg * 8];
    const bf16* b0 = &BT[(size_t)(n0 + l15) * K + lg * 8];

    for (int k0 = 0; k0 < K; k0 += 32) {
        bf16x8 a[2], b[2];
        a[0] = *reinterpret_cast<const bf16x8*>(a0 + k0);
        a[1] = *reinterpret_cast<const bf16x8*>(a0 + (size_t)16 * K + k0);
        b[0] = *reinterpret_cast<const bf16x8*>(b0 + k0);
        b[1] = *reinterpret_cast<const bf16x8*>(b0 + (size_t)16 * K + k0);
        #pragma unroll
        for (int i = 0; i < 2; ++i)
            #pragma unroll
            for (int j = 0; j < 2; ++j)
                acc[i][j] = __builtin_amdgcn_mfma_f32_16x16x32_bf16(a[i], b[j], acc[i][j], 0, 0, 0);
    }

    #pragma unroll
    for (int i = 0; i < 2; ++i) {
        #pragma unroll
        for (int j = 0; j < 2; ++j) {
            const int col = n0 + j * 16 + l15;
            const float bs = bias[col];
            #pragma unroll
            for (int r = 0; r < 4; ++r) {
                const int row = m0 + i * 16 + lg * 4 + r;
                float val = acc[i][j][r] + bs;
                if (RELU) val = fmaxf(val, 0.f);
                if constexpr (OUT_MODE == 0)
                    Cf[(size_t)row * N + col] = val;
                if constexpr (OUT_MODE == 2)
                    Cb[(size_t)row * N + col] = (bf16)val;
            }
        }
    }
}

// ---------------------------------------------------------------------------
// 4-wave fused QKV projections: grid z = 0(q) / 1(k) / 2(v).
// ---------------------------------------------------------------------------
__global__ __launch_bounds__(256)
void qkv_gemm(const bf16* __restrict__ xT, const bf16* __restrict__ yT,
              const bf16* __restrict__ WqT, const bf16* __restrict__ WkT,
              const bf16* __restrict__ WvT,
              const float* __restrict__ bq, const float* __restrict__ bk,
              const float* __restrict__ bv,
              bf16* __restrict__ qb, bf16* __restrict__ kbb, bf16* __restrict__ vTb,
              float kscale) {
    const int z = blockIdx.z;
    const bf16* A  = (z == 0) ? xT : yT;
    const bf16* BT = (z == 0) ? WqT : (z == 1) ? WkT : WvT;
    const float* bias = (z == 0) ? bq : (z == 1) ? bk : bv;

    const int tid = threadIdx.x;
    const int w = tid >> 6, l = tid & 63;
    const int l15 = l & 15, lg = l >> 4;
    const int m0 = blockIdx.x * 64 + (w >> 1) * 32;
    const int n0 = blockIdx.y * 64 + (w & 1) * 32;

    f32x4 acc[2][2] = {};
    const bf16* a0 = &A[(size_t)(m0 + l15) * CCH + lg * 8];
    const bf16* b0 = &BT[(size_t)(n0 + l15) * CCH + lg * 8];

    for (int k0 = 0; k0 < CCH; k0 += 32) {
        bf16x8 a[2], b[2];
        a[0] = *reinterpret_cast<const bf16x8*>(a0 + k0);
        a[1] = *reinterpret_cast<const bf16x8*>(a0 + (size_t)16 * CCH + k0);
        b[0] = *reinterpret_cast<const bf16x8*>(b0 + k0);
        b[1] = *reinterpret_cast<const bf16x8*>(b0 + (size_t)16 * CCH + k0);
        #pragma unroll
        for (int i = 0; i < 2; ++i)
            #pragma unroll
            for (int j = 0; j < 2; ++j)
                acc[i][j] = __builtin_amdgcn_mfma_f32_16x16x32_bf16(a[i], b[j], acc[i][j], 0, 0, 0);
    }

    const float sc = (z == 1) ? kscale : 1.f;
    #pragma unroll
    for (int i = 0; i < 2; ++i) {
        #pragma unroll
        for (int j = 0; j < 2; ++j) {
            const int col = n0 + j * 16 + l15;
            const float bs = bias[col];
            #pragma unroll
            for (int r = 0; r < 4; ++r) {
                const int row = m0 + i * 16 + lg * 4 + r;
                float val = acc[i][j][r] + bs;
                if (z == 2)
                    vTb[((size_t)(col >> 5) * VROWS + (col & 31)) * SQ + row] = (bf16)val;
                else if (z == 1)
                    kbb[(size_t)row * CCH + col] = (bf16)(val * sc);
                else
                    qb[(size_t)row * CCH + col] = (bf16)val;
            }
        }
    }
}

// ---------------------------------------------------------------------------
// Fused Wo projection + residual + LN1, row-panel form (proven in r14).
// ---------------------------------------------------------------------------
__global__ __launch_bounds__(256)
void wo_ln1(const bf16* __restrict__ atb, const bf16* __restrict__ WoT,
            const float* __restrict__ bo, const bf16* __restrict__ qb,
            const float* __restrict__ g, const float* __restrict__ beta,
            float* __restrict__ ln1, bf16* __restrict__ ln1b) {
    const int tid = threadIdx.x;
    const int w = tid >> 6, l = tid & 63;
    const int l15 = l & 15, lg = l >> 4;
    const int mr = blockIdx.x * 16;
    const int n0 = w * 64;

    f32x4 acc[4] = {};
    const bf16* a0 = &atb[(size_t)(mr + l15) * CCH + lg * 8];
    const bf16* b0 = &WoT[(size_t)(n0 + l15) * CCH + lg * 8];
    #pragma unroll
    for (int k0 = 0; k0 < CCH; k0 += 32) {
        bf16x8 a = *reinterpret_cast<const bf16x8*>(a0 + k0);
        #pragma unroll
        for (int j = 0; j < 4; ++j) {
            bf16x8 b = *reinterpret_cast<const bf16x8*>(b0 + (size_t)j * 16 * CCH + k0);
            acc[j] = __builtin_amdgcn_mfma_f32_16x16x32_bf16(a, b, acc[j], 0, 0, 0);
        }
    }

    float val[4][4];
    float rsum[4] = {0.f, 0.f, 0.f, 0.f}, rsq[4] = {0.f, 0.f, 0.f, 0.f};
    #pragma unroll
    for (int j = 0; j < 4; ++j) {
        const int col = n0 + j * 16 + l15;
        const float bs = bo[col];
        #pragma unroll
        for (int r = 0; r < 4; ++r) {
            const int row = mr + lg * 4 + r;
            float v = acc[j][r] + bs + (float)qb[(size_t)row * CCH + col];
            val[j][r] = v;
            rsum[r] += v;
            rsq[r] += v * v;
        }
    }
    #pragma unroll
    for (int r = 0; r < 4; ++r) {
        #pragma unroll
        for (int off = 1; off < 16; off <<= 1) {
            rsum[r] += __shfl_xor(rsum[r], off);
            rsq[r]  += __shfl_xor(rsq[r], off);
        }
    }
    __shared__ float ssum[4][16], ssq[4][16];
    if (l15 == 0) {
        #pragma unroll
        for (int r = 0; r < 4; ++r) {
            ssum[w][lg * 4 + r] = rsum[r];
            ssq[w][lg * 4 + r]  = rsq[r];
        }
    }
    __syncthreads();
    float mu_[4], rs_[4];
    #pragma unroll
    for (int r = 0; r < 4; ++r) {
        const int row = lg * 4 + r;
        float s = (ssum[0][row] + ssum[1][row]) + (ssum[2][row] + ssum[3][row]);
        float q = (ssq[0][row] + ssq[1][row]) + (ssq[2][row] + ssq[3][row]);
        float mu = s * (1.0f / CCH);
        float var = q * (1.0f / CCH) - mu * mu;
        mu_[r] = mu;
        rs_[r] = rsqrtf(var + LN_EPS);
    }
    #pragma unroll
    for (int j = 0; j < 4; ++j) {
        const int col = n0 + j * 16 + l15;
        const float gg = g[col], bb = beta[col];
        #pragma unroll
        for (int r = 0; r < 4; ++r) {
            const int row = mr + lg * 4 + r;
            float res = (val[j][r] - mu_[r]) * rs_[r] * gg + bb;
            ln1[(size_t)row * CCH + col] = res;
            ln1b[(size_t)row * CCH + col] = (bf16)res;
        }
    }
}

// ---------------------------------------------------------------------------
// Fused FFN2 + residual + LN2 + output transpose, row-panel form (r15 proven).
// ---------------------------------------------------------------------------
__global__ __launch_bounds__(256)
void ffn2_ln2_t(const bf16* __restrict__ h1, const bf16* __restrict__ W2T,
                const float* __restrict__ bf2, const float* __restrict__ ln1,
                const float* __restrict__ g, const float* __restrict__ beta,
                float* __restrict__ out) {
    const int tid = threadIdx.x;
    const int w = tid >> 6, l = tid & 63;
    const int l15 = l & 15, lg = l >> 4;
    const int mr = blockIdx.x * 16;
    const int n0 = w * 64;

    f32x4 acc[4] = {};
    const bf16* a0 = &h1[(size_t)(mr + l15) * 1024 + lg * 8];
    const bf16* b0 = &W2T[(size_t)(n0 + l15) * 1024 + lg * 8];
    for (int k0 = 0; k0 < 1024; k0 += 32) {
        bf16x8 a = *reinterpret_cast<const bf16x8*>(a0 + k0);
        #pragma unroll
        for (int j = 0; j < 4; ++j) {
            bf16x8 b = *reinterpret_cast<const bf16x8*>(b0 + (size_t)j * 16 * 1024 + k0);
            acc[j] = __builtin_amdgcn_mfma_f32_16x16x32_bf16(a, b, acc[j], 0, 0, 0);
        }
    }

    float val[4][4];
    float rsum[4] = {0.f, 0.f, 0.f, 0.f}, rsq[4] = {0.f, 0.f, 0.f, 0.f};
    #pragma unroll
    for (int j = 0; j < 4; ++j) {
        const int col = n0 + j * 16 + l15;
        const float bs = bf2[col];
        #pragma unroll
        for (int r = 0; r < 4; ++r) {
            const int row = mr + lg * 4 + r;
            float v = acc[j][r] + bs + ln1[(size_t)row * CCH + col];
            val[j][r] = v;
            rsum[r] += v;
            rsq[r] += v * v;
        }
    }
    #pragma unroll
    for (int r = 0; r < 4; ++r) {
        #pragma unroll
        for (int off = 1; off < 16; off <<= 1) {
            rsum[r] += __shfl_xor(rsum[r], off);
            rsq[r]  += __shfl_xor(rsq[r], off);
        }
    }
    __shared__ float ssum[4][16], ssq[4][16];
    if (l15 == 0) {
        #pragma unroll
        for (int r = 0; r < 4; ++r) {
            ssum[w][lg * 4 + r] = rsum[r];
            ssq[w][lg * 4 + r]  = rsq[r];
        }
    }
    __syncthreads();
    float mu_[4], rs_[4];
    #pragma unroll
    for (int r = 0; r < 4; ++r) {
        const int row = lg * 4 + r;
        float s = (ssum[0][row] + ssum[1][row]) + (ssum[2][row] + ssum[3][row]);
        float q = (ssq[0][row] + ssq[1][row]) + (ssq[2][row] + ssq[3][row]);
        float mu = s * (1.0f / CCH);
        float var = q * (1.0f / CCH) - mu * mu;
        mu_[r] = mu;
        rs_[r] = rsqrtf(var + LN_EPS);
    }

    __shared__ float tile[256][17];
    #pragma unroll
    for (int j = 0; j < 4; ++j) {
        const int col = n0 + j * 16 + l15;
        const float gg = g[col], bb = beta[col];
        #pragma unroll
        for (int r = 0; r < 4; ++r)
            tile[col][lg * 4 + r] = (val[j][r] - mu_[r]) * rs_[r] * gg + bb;
    }
    __syncthreads();
    const int c = tid;
    float* orow = &out[(size_t)c * SQ + mr];
    #pragma unroll
    for (int q4 = 0; q4 < 4; ++q4) {
        float4 o4 = {tile[c][q4 * 4], tile[c][q4 * 4 + 1],
                     tile[c][q4 * 4 + 2], tile[c][q4 * 4 + 3]};
        *reinterpret_cast<float4*>(orow + q4 * 4) = o4;
    }
}

// ---------------------------------------------------------------------------
// MFMA flash attention v12: quad-Q, swapped QK^T, no-max softmax, MFMA
// row-sum, v_exp, and REGISTER-ONLY PV via K=16 MFMA (the swapped-QK^T
// D-quad IS the K=16 B-fragment).  Zero LDS, zero bank conflicts, no
// lgkmcnt in the hot loop.  V 8B-fragment traffic amortized by quad-Q.
// ---------------------------------------------------------------------------
__global__ __launch_bounds__(256)
void flash_attn12(const bf16* __restrict__ qb, const bf16* __restrict__ kb,
                  const bf16* __restrict__ vT, bf16* __restrict__ Op,
                  float* __restrict__ Lp) {
    const int fid = blockIdx.x + 16 * (blockIdx.y + NH * blockIdx.z);
    const int nid = (fid & 7) * 64 + (fid >> 3);
    const int q0 = (nid & 15) * 256;
    const int h  = (nid >> 4) & 7;
    const int sp = nid >> 7;

    const int tid = threadIdx.x;
    const int w = tid >> 6, l = tid & 63;
    const int l15 = l & 15, lg = l >> 4;

#if !HAVE_MFMA16
    __shared__ unsigned int Sb[4][2][8][72];
#endif

    bf16x8 aq[4];
    #pragma unroll
    for (int su = 0; su < 4; ++su)
        aq[su] = *reinterpret_cast<const bf16x8*>(
            &qb[(size_t)(q0 + su * 64 + w * 16 + l15) * CCH + h * HD + lg * 8]);

    f32x4 o[4][2] = {};
    f32x4 o2[4] = {};   // row-sum accumulators (ones-row MFMA)

    const bf16* kfrag = &kb[(size_t)l15 * CCH + h * HD + lg * 8];
#if HAVE_MFMA16
    const bf16* vfrag16 = &vT[((size_t)h * VROWS + l15) * SQ + lg * 4];
#else
    const bf16* vfrag = &vT[((size_t)h * VROWS + l15) * SQ + lg * 8];
#endif

    const int kt0 = sp * (SQ / NSPLIT / 64);
    const int kt1 = kt0 + (SQ / NSPLIT / 64);

    for (int kt = kt0; kt < kt1; ++kt) {
        const int kb0 = kt * 64;

        bf16x8 kf[4];
        #pragma unroll
        for (int t = 0; t < 4; ++t)
            kf[t] = *reinterpret_cast<const bf16x8*>(kfrag + (size_t)(kb0 + t * 16) * CCH);

#if HAVE_MFMA16
        // V K=16 fragments: [dh][t], 8B each, shared by all 4 subtiles
        s16x4 vf[3][4];
        #pragma unroll
        for (int dh = 0; dh < 3; ++dh)
            #pragma unroll
            for (int t = 0; t < 4; ++t)
                vf[dh][t] = *reinterpret_cast<const s16x4*>(
                    vfrag16 + (size_t)dh * 16 * SQ + kb0 + t * 16);

        #pragma unroll
        for (int su = 0; su < 4; ++su) {
            f32x4 s[4];
            #pragma unroll
            for (int t = 0; t < 4; ++t)
                s[t] = __builtin_amdgcn_mfma_f32_16x16x32_bf16(
                    kf[t], aq[su], (f32x4){0.f, 0.f, 0.f, 0.f}, 0, 0, 0);

            #pragma unroll
            for (int t = 0; t < 4; ++t) {
                unsigned int u0 = __builtin_bit_cast(unsigned int, fast_exp2(s[t][0]));
                unsigned int u1 = __builtin_bit_cast(unsigned int, fast_exp2(s[t][1]));
                unsigned int u2 = __builtin_bit_cast(unsigned int, fast_exp2(s[t][2]));
                unsigned int u3 = __builtin_bit_cast(unsigned int, fast_exp2(s[t][3]));
                union { unsigned int u[2]; s16x4 v; } pb;
                pb.u[0] = __builtin_amdgcn_perm(u1, u0, 0x07060302u);
                pb.u[1] = __builtin_amdgcn_perm(u3, u2, 0x07060302u);
                o[su][0] = __builtin_amdgcn_mfma_f32_16x16x16bf16_1k(
                    vf[0][t], pb.v, o[su][0], 0, 0, 0);
                o[su][1] = __builtin_amdgcn_mfma_f32_16x16x16bf16_1k(
                    vf[1][t], pb.v, o[su][1], 0, 0, 0);
                o2[su]   = __builtin_amdgcn_mfma_f32_16x16x16bf16_1k(
                    vf[2][t], pb.v, o2[su], 0, 0, 0);
            }
        }
#else
        // fallback: v11 LDS-relayout K=32 path
        bf16x8 vf[3][2];
        #pragma unroll
        for (int dh = 0; dh < 3; ++dh)
            #pragma unroll
            for (int kh = 0; kh < 2; ++kh)
                vf[dh][kh] = *reinterpret_cast<const bf16x8*>(
                    vfrag + (size_t)dh * 16 * SQ + kb0 + kh * 32);

        #pragma unroll
        for (int su = 0; su < 4; ++su) {
            const int par = su & 1;
            f32x4 s[4];
            #pragma unroll
            for (int t = 0; t < 4; ++t)
                s[t] = __builtin_amdgcn_mfma_f32_16x16x32_bf16(
                    kf[t], aq[su], (f32x4){0.f, 0.f, 0.f, 0.f}, 0, 0, 0);

            #pragma unroll
            for (int t = 0; t < 4; ++t) {
                unsigned int u0 = __builtin_bit_cast(unsigned int, fast_exp2(s[t][0]));
                unsigned int u1 = __builtin_bit_cast(unsigned int, fast_exp2(s[t][1]));
                unsigned int u2 = __builtin_bit_cast(unsigned int, fast_exp2(s[t][2]));
                unsigned int u3 = __builtin_bit_cast(unsigned int, fast_exp2(s[t][3]));
                Sb[w][par][t * 2 + 0][l] = __builtin_amdgcn_perm(u1, u0, 0x07060302u);
                Sb[w][par][t * 2 + 1][l] = __builtin_amdgcn_perm(u3, u2, 0x07060302u);
            }

            #pragma unroll
            for (int kh = 0; kh < 2; ++kh) {
                const int sbase = kh * 4 + (lg >> 1) * 2;
                const int i0 = l15 + 16 * ((lg & 1) * 2);
                const int i1 = i0 + 16;
                union { unsigned int u[4]; bf16x8 v; } pb;
                pb.u[0] = Sb[w][par][sbase + 0][i0];
                pb.u[1] = Sb[w][par][sbase + 1][i0];
                pb.u[2] = Sb[w][par][sbase + 0][i1];
                pb.u[3] = Sb[w][par][sbase + 1][i1];
                #pragma unroll
                for (int dh = 0; dh < 2; ++dh)
                    o[su][dh] = __builtin_amdgcn_mfma_f32_16x16x32_bf16(
                        vf[dh][kh], pb.v, o[su][dh], 0, 0, 0);
                o2[su] = __builtin_amdgcn_mfma_f32_16x16x32_bf16(
                    vf[2][kh], pb.v, o2[su], 0, 0, 0);
            }
        }
#endif
    }

    const size_t obase = ((size_t)sp * NH + h) * HD;
    #pragma unroll
    for (int su = 0; su < 4; ++su) {
        const int qrow = q0 + su * 64 + w * 16 + l15;
        #pragma unroll
        for (int dh = 0; dh < 2; ++dh)
            #pragma unroll
            for (int r = 0; r < 4; ++r)
                Op[(obase + dh * 16 + lg * 4 + r) * SQ + qrow] = (bf16)o[su][dh][r];
        if (lg == 0)
            Lp[((size_t)sp * NH + h) * SQ + qrow] = o2[su][0];
    }
}

// ---------------------------------------------------------------------------
// Merge NSPLIT raw partial O^T [d][q] tiles -> atb [S][C] bf16.
// ---------------------------------------------------------------------------
__global__ __launch_bounds__(256)
void attn_merge3(const bf16* __restrict__ Op, const float* __restrict__ Lp,
                 bf16* __restrict__ atb) {
    const int h = blockIdx.y;
    const int q0 = blockIdx.x * 64;
    const int t = threadIdx.x;
    __shared__ float sInv[64];
    __shared__ float trans[32][65];

    if (t < 64) {
        float L = 0.f;
        #pragma unroll
        for (int sp = 0; sp < NSPLIT; ++sp)
            L += Lp[((size_t)sp * NH + h) * SQ + q0 + t];
        sInv[t] = 1.0f / L;
    }
    __syncthreads();

    const int q = t & 63, dg = t >> 6;
    float a[8] = {0.f, 0.f, 0.f, 0.f, 0.f, 0.f, 0.f, 0.f};
    for (int sp = 0; sp < NSPLIT; ++sp) {
        const size_t rb = ((size_t)sp * NH + h) * HD;
        #pragma unroll
        for (int i = 0; i < 8; ++i) {
            const int d = i * 4 + dg;
            a[i] += (float)Op[(rb + d) * SQ + q0 + q];
        }
    }
    const float invq = sInv[q];
    #pragma unroll
    for (int i = 0; i < 8; ++i)
        trans[i * 4 + dg][q] = a[i] * invq;
    __syncthreads();

    const int oq = t >> 2, od = (t & 3) * 8;
    bf16x8 o8;
    #pragma unroll
    for (int j = 0; j < 8; ++j) o8[j] = (bf16)trans[od + j][oq];
    *reinterpret_cast<bf16x8*>(&atb[(size_t)(q0 + oq) * CCH + h * HD + od]) = o8;
}

// ---------------------------------------------------------------------------
extern "C" void kernel_launch(void* const* d_in, const int* in_sizes, int n_in,
                              void* d_out, int out_size, void* d_ws, size_t ws_size,
                              hipStream_t stream) {
    const float* lidar = (const float*)d_in[0];
    const float* image = (const float*)d_in[1];
    const float* Wq  = (const float*)d_in[2];
    const float* bq  = (const float*)d_in[3];
    const float* Wk  = (const float*)d_in[4];
    const float* bk  = (const float*)d_in[5];
    const float* Wv  = (const float*)d_in[6];
    const float* bv  = (const float*)d_in[7];
    const float* Wo  = (const float*)d_in[8];
    const float* bo  = (const float*)d_in[9];
    const float* g1  = (const float*)d_in[10];
    const float* b1  = (const float*)d_in[11];
    const float* W1  = (const float*)d_in[12];
    const float* bf1 = (const float*)d_in[13];
    const float* W2  = (const float*)d_in[14];
    const float* bf2 = (const float*)d_in[15];
    const float* g2  = (const float*)d_in[16];
    const float* b2  = (const float*)d_in[17];
    float* out = (float*)d_out;

    // workspace layout (aliased; peak 23.5 MB).  Lp (512K) in d_out until merge.
    char* ws = (char*)d_ws;
    const size_t KB = 1024;
    bf16* W2T = (bf16*)(ws + 0);                 // [0,512K)     live -> ffn2_ln2_t
    bf16* W1T = (bf16*)(ws + 512 * KB);          // [512K,1M)    live -> ffn1
    bf16* WoT = (bf16*)(ws + 1024 * KB);         // [1,1.125M)   live -> wo_ln1
    bf16* WqT = (bf16*)(ws + 1152 * KB);         // dead after qkv
    bf16* WkT = (bf16*)(ws + 1280 * KB);
    bf16* WvT = (bf16*)(ws + 1408 * KB);         // ends 1.5M
    bf16* qb  = (bf16*)(ws + 1536 * KB);         // [1.5,3.5M)   live -> wo_ln1
    bf16* kbb = (bf16*)(ws + 3584 * KB);         // [3.5,5.5M)   dead after flash
    bf16* vTb = (bf16*)(ws + 5632 * KB);         // [5.5,8.5M)   padded; dead after flash
    bf16* xT  = (bf16*)(ws + 8704 * KB);         // [8.5,10.5M)  dead after qkv
    bf16* yT  = (bf16*)(ws + 10752 * KB);        // [10.5,12.5M) dead after qkv
    bf16* Op  = (bf16*)(ws + 8704 * KB);         // [8.5,16.5M)  overlays xT/yT
    float* Lp = (float*)d_out;                   // 512K scratch in d_out
    bf16* atb = (bf16*)(ws + 3584 * KB);         // reuses kbb; dead after wo_ln1
    float* ln1 = (float*)(ws + 19968 * KB);      // [19.5,23.5M) live -> ffn2_ln2_t
    bf16* ln1b = (bf16*)(ws + 5632 * KB);        // [5.5,7.5M)   reuses vTb; dead after ffn1
    bf16* h1  = (bf16*)(ws + 9728 * KB);         // [9.5,17.5M)  dead after ffn2_ln2_t

    // 1/sqrt(32) * log2(e) folded into K -> scores already in log2 domain
    const float qscale = 0.17677669529663687f * 1.4426950408889634f;
    dim3 blk(256);

    // all layout conversions in one launch
    cvt_all<<<dim3(2880), blk, 0, stream>>>(lidar, image, xT, yT,
                                            Wq, Wk, Wv, Wo, W1, W2,
                                            WqT, WkT, WvT, WoT, W1T, W2T, vTb);
    // fused QKV projections
    qkv_gemm<<<dim3(64, 4, 3), blk, 0, stream>>>(xT, yT, WqT, WkT, WvT,
                                                 bq, bk, bv, qb, kbb, vTb, qscale);
    // attention (split-KV x4, swapped-operand, no-max, MFMA row-sum, reg PV)
    flash_attn12<<<dim3(SQ / 256, NH, NSPLIT), blk, 0, stream>>>(qb, kbb, vTb, Op, Lp);
    attn_merge3<<<dim3(SQ / 64, NH), blk, 0, stream>>>(Op, Lp, atb);
    // fused Wo projection + residual + LN1 (row-panel)
    wo_ln1<<<dim3(SQ / 16), blk, 0, stream>>>(atb, WoT, bo, qb, g1, b1, ln1, ln1b);
    // FFN1
    gemm_mfma<256, 2, true><<<dim3(64, 16), blk, 0, stream>>>(ln1b, W1T, bf1, nullptr, h1, 1024);
    // fused FFN2 + residual + LN2 + transpose (row-panel)
    ffn2_ln2_t<<<dim3(SQ / 16), blk, 0, stream>>>(h1, W2T, bf2, ln1, g2, b2, out);
}

// Round 17
// 126.731 us; speedup vs baseline: 1.1134x; 1.1134x over previous
//
#include <hip/hip_runtime.h>

#define SQ 4096      // sequence length = 64*64
#define CCH 256      // channels
#define NH 8         // heads
#define HD 32        // head dim
#define LN_EPS 1e-5f
#define NSPLIT 8     // kv splits per head
#define VROWS 33     // V^T rows per head: 32 data + 1 ones row (+15 global guard)

typedef __bf16 bf16x8 __attribute__((ext_vector_type(8)));
typedef float f32x4 __attribute__((ext_vector_type(4)));
using bf16 = __bf16;

// Raw hardware 2^x (exp2f lowers to a ~20-VALU OCML guarded sequence;
// inputs here are bounded so the fixups are dead weight).
__device__ __forceinline__ float fast_exp2(float x) {
#if defined(__has_builtin)
#if __has_builtin(__builtin_amdgcn_exp2f)
    return __builtin_amdgcn_exp2f(x);
#else
    float r;
    asm("v_exp_f32 %0, %1" : "=v"(r) : "v"(x));
    return r;
#endif
#else
    float r;
    asm("v_exp_f32 %0, %1" : "=v"(r) : "v"(x));
    return r;
#endif
}

// ---------------------------------------------------------------------------
// Tile transpose + fp32->bf16 convert: src [R][Ccol] f32 -> dst [Ccol][R] bf16
// ---------------------------------------------------------------------------
__device__ __forceinline__ void tile_tc(const float* __restrict__ src, bf16* __restrict__ dst,
                                        int R, int Ccol, int ti, int tj) {
    __shared__ float t[32][33];
    const int tx = threadIdx.x & 31;
    const int ty = threadIdx.x >> 5;   // 0..7
    const int i0 = ti * 32, j0 = tj * 32;
    #pragma unroll
    for (int i = 0; i < 32; i += 8)
        t[ty + i][tx] = src[(size_t)(i0 + ty + i) * Ccol + j0 + tx];
    __syncthreads();
    #pragma unroll
    for (int i = 0; i < 32; i += 8)
        dst[(size_t)(j0 + ty + i) * R + i0 + tx] = (bf16)t[tx][ty + i];
}

// ---------------------------------------------------------------------------
// ALL conversions in one launch (2880 blocks).
// Pad rows: per head h, row h*33+32 = 1.0 (ones row for MFMA row-sum);
// global guard rows 264..278 = 0 (keep h=7's A-fragment reads in-bounds).
// ---------------------------------------------------------------------------
__global__ __launch_bounds__(256)
void cvt_all(const float* __restrict__ x, const float* __restrict__ y,
             bf16* __restrict__ xT, bf16* __restrict__ yT,
             const float* Wq, const float* Wk, const float* Wv, const float* Wo,
             const float* W1, const float* W2,
             bf16* WqT, bf16* WkT, bf16* WvT, bf16* WoT, bf16* W1T, bf16* W2T,
             bf16* vTb) {
    const int id = blockIdx.x;
    if (id < 2048) {
        const int z = id >> 10;
        const int t = id & 1023;
        const float* s = z ? y : x;
        bf16* d = z ? yT : xT;
        tile_tc(s, d, CCH, SQ, t >> 7, t & 127);
        return;
    }
    const int wid = id - 2048;
    if (wid < 256) {
        const int w = wid >> 6, local = wid & 63;
        const float* s = (w == 0) ? Wq : (w == 1) ? Wk : (w == 2) ? Wv : Wo;
        bf16* d = (w == 0) ? WqT : (w == 1) ? WkT : (w == 2) ? WvT : WoT;
        tile_tc(s, d, 256, 256, local >> 3, local & 7);
    } else if (wid < 512) {
        const int local = wid - 256;
        tile_tc(W1, W1T, 256, 1024, local >> 5, local & 31);
    } else if (wid < 768) {
        const int local = wid - 512;
        tile_tc(W2, W2T, 1024, 256, local >> 3, local & 7);
    } else {
        // pad rows: 23 logical rows x 4096 elems (8 ones rows + 15 guard rows)
        const int local = wid - 768;                 // 0..63
        const int f = (local * 256 + threadIdx.x) * 8;
        if (f < 23 * 4096) {
            const int pr = f >> 12;                  // 0..22
            const int col = f & 4095;
            const size_t grow = (pr < 8) ? ((size_t)pr * VROWS + 32)
                                         : ((size_t)8 * VROWS + (pr - 8));
            const bf16 val = (bf16)((pr < 8) ? 1.0f : 0.0f);
            bf16x8 v8;
            #pragma unroll
            for (int e = 0; e < 8; ++e) v8[e] = val;
            *reinterpret_cast<bf16x8*>(vTb + grow * SQ + col) = v8;
        }
    }
}

// ---------------------------------------------------------------------------
// 4-wave MFMA GEMM: 64x64 tile, wave -> 32x32, reg fragments.
// OUT_MODE: 0 = f32; 2 = bf16.
// ---------------------------------------------------------------------------
template <int K, int OUT_MODE, bool RELU>
__global__ __launch_bounds__(256)
void gemm_mfma(const bf16* __restrict__ A, const bf16* __restrict__ BT,
               const float* __restrict__ bias, float* __restrict__ Cf,
               bf16* __restrict__ Cb, int N) {
    const int tid = threadIdx.x;
    const int w = tid >> 6, l = tid & 63;
    const int l15 = l & 15, lg = l >> 4;
    const int m0 = blockIdx.x * 64 + (w >> 1) * 32;
    const int n0 = blockIdx.y * 64 + (w & 1) * 32;

    f32x4 acc[2][2] = {};
    const bf16* a0 = &A[(size_t)(m0 + l15) * K + lg * 8];
    const bf16* b0 = &BT[(size_t)(n0 + l15) * K + lg * 8];

    for (int k0 = 0; k0 < K; k0 += 32) {
        bf16x8 a[2], b[2];
        a[0] = *reinterpret_cast<const bf16x8*>(a0 + k0);
        a[1] = *reinterpret_cast<const bf16x8*>(a0 + (size_t)16 * K + k0);
        b[0] = *reinterpret_cast<const bf16x8*>(b0 + k0);
        b[1] = *reinterpret_cast<const bf16x8*>(b0 + (size_t)16 * K + k0);
        #pragma unroll
        for (int i = 0; i < 2; ++i)
            #pragma unroll
            for (int j = 0; j < 2; ++j)
                acc[i][j] = __builtin_amdgcn_mfma_f32_16x16x32_bf16(a[i], b[j], acc[i][j], 0, 0, 0);
    }

    #pragma unroll
    for (int i = 0; i < 2; ++i) {
        #pragma unroll
        for (int j = 0; j < 2; ++j) {
            const int col = n0 + j * 16 + l15;
            const float bs = bias[col];
            #pragma unroll
            for (int r = 0; r < 4; ++r) {
                const int row = m0 + i * 16 + lg * 4 + r;
                float val = acc[i][j][r] + bs;
                if (RELU) val = fmaxf(val, 0.f);
                if constexpr (OUT_MODE == 0)
                    Cf[(size_t)row * N + col] = val;
                if constexpr (OUT_MODE == 2)
                    Cb[(size_t)row * N + col] = (bf16)val;
            }
        }
    }
}

// ---------------------------------------------------------------------------
// 4-wave fused QKV projections: grid z = 0(q) / 1(k) / 2(v).
// ---------------------------------------------------------------------------
__global__ __launch_bounds__(256)
void qkv_gemm(const bf16* __restrict__ xT, const bf16* __restrict__ yT,
              const bf16* __restrict__ WqT, const bf16* __restrict__ WkT,
              const bf16* __restrict__ WvT,
              const float* __restrict__ bq, const float* __restrict__ bk,
              const float* __restrict__ bv,
              bf16* __restrict__ qb, bf16* __restrict__ kbb, bf16* __restrict__ vTb,
              float kscale) {
    const int z = blockIdx.z;
    const bf16* A  = (z == 0) ? xT : yT;
    const bf16* BT = (z == 0) ? WqT : (z == 1) ? WkT : WvT;
    const float* bias = (z == 0) ? bq : (z == 1) ? bk : bv;

    const int tid = threadIdx.x;
    const int w = tid >> 6, l = tid & 63;
    const int l15 = l & 15, lg = l >> 4;
    const int m0 = blockIdx.x * 64 + (w >> 1) * 32;
    const int n0 = blockIdx.y * 64 + (w & 1) * 32;

    f32x4 acc[2][2] = {};
    const bf16* a0 = &A[(size_t)(m0 + l15) * CCH + lg * 8];
    const bf16* b0 = &BT[(size_t)(n0 + l15) * CCH + lg * 8];

    for (int k0 = 0; k0 < CCH; k0 += 32) {
        bf16x8 a[2], b[2];
        a[0] = *reinterpret_cast<const bf16x8*>(a0 + k0);
        a[1] = *reinterpret_cast<const bf16x8*>(a0 + (size_t)16 * CCH + k0);
        b[0] = *reinterpret_cast<const bf16x8*>(b0 + k0);
        b[1] = *reinterpret_cast<const bf16x8*>(b0 + (size_t)16 * CCH + k0);
        #pragma unroll
        for (int i = 0; i < 2; ++i)
            #pragma unroll
            for (int j = 0; j < 2; ++j)
                acc[i][j] = __builtin_amdgcn_mfma_f32_16x16x32_bf16(a[i], b[j], acc[i][j], 0, 0, 0);
    }

    const float sc = (z == 1) ? kscale : 1.f;
    #pragma unroll
    for (int i = 0; i < 2; ++i) {
        #pragma unroll
        for (int j = 0; j < 2; ++j) {
            const int col = n0 + j * 16 + l15;
            const float bs = bias[col];
            #pragma unroll
            for (int r = 0; r < 4; ++r) {
                const int row = m0 + i * 16 + lg * 4 + r;
                float val = acc[i][j][r] + bs;
                if (z == 2)
                    vTb[((size_t)(col >> 5) * VROWS + (col & 31)) * SQ + row] = (bf16)val;
                else if (z == 1)
                    kbb[(size_t)row * CCH + col] = (bf16)(val * sc);
                else
                    qb[(size_t)row * CCH + col] = (bf16)val;
            }
        }
    }
}

// ---------------------------------------------------------------------------
// Fused Wo projection + residual + LN1, row-panel form (proven in r14).
// ---------------------------------------------------------------------------
__global__ __launch_bounds__(256)
void wo_ln1(const bf16* __restrict__ atb, const bf16* __restrict__ WoT,
            const float* __restrict__ bo, const bf16* __restrict__ qb,
            const float* __restrict__ g, const float* __restrict__ beta,
            float* __restrict__ ln1, bf16* __restrict__ ln1b) {
    const int tid = threadIdx.x;
    const int w = tid >> 6, l = tid & 63;
    const int l15 = l & 15, lg = l >> 4;
    const int mr = blockIdx.x * 16;
    const int n0 = w * 64;

    f32x4 acc[4] = {};
    const bf16* a0 = &atb[(size_t)(mr + l15) * CCH + lg * 8];
    const bf16* b0 = &WoT[(size_t)(n0 + l15) * CCH + lg * 8];
    #pragma unroll
    for (int k0 = 0; k0 < CCH; k0 += 32) {
        bf16x8 a = *reinterpret_cast<const bf16x8*>(a0 + k0);
        #pragma unroll
        for (int j = 0; j < 4; ++j) {
            bf16x8 b = *reinterpret_cast<const bf16x8*>(b0 + (size_t)j * 16 * CCH + k0);
            acc[j] = __builtin_amdgcn_mfma_f32_16x16x32_bf16(a, b, acc[j], 0, 0, 0);
        }
    }

    float val[4][4];
    float rsum[4] = {0.f, 0.f, 0.f, 0.f}, rsq[4] = {0.f, 0.f, 0.f, 0.f};
    #pragma unroll
    for (int j = 0; j < 4; ++j) {
        const int col = n0 + j * 16 + l15;
        const float bs = bo[col];
        #pragma unroll
        for (int r = 0; r < 4; ++r) {
            const int row = mr + lg * 4 + r;
            float v = acc[j][r] + bs + (float)qb[(size_t)row * CCH + col];
            val[j][r] = v;
            rsum[r] += v;
            rsq[r] += v * v;
        }
    }
    #pragma unroll
    for (int r = 0; r < 4; ++r) {
        #pragma unroll
        for (int off = 1; off < 16; off <<= 1) {
            rsum[r] += __shfl_xor(rsum[r], off);
            rsq[r]  += __shfl_xor(rsq[r], off);
        }
    }
    __shared__ float ssum[4][16], ssq[4][16];
    if (l15 == 0) {
        #pragma unroll
        for (int r = 0; r < 4; ++r) {
            ssum[w][lg * 4 + r] = rsum[r];
            ssq[w][lg * 4 + r]  = rsq[r];
        }
    }
    __syncthreads();
    float mu_[4], rs_[4];
    #pragma unroll
    for (int r = 0; r < 4; ++r) {
        const int row = lg * 4 + r;
        float s = (ssum[0][row] + ssum[1][row]) + (ssum[2][row] + ssum[3][row]);
        float q = (ssq[0][row] + ssq[1][row]) + (ssq[2][row] + ssq[3][row]);
        float mu = s * (1.0f / CCH);
        float var = q * (1.0f / CCH) - mu * mu;
        mu_[r] = mu;
        rs_[r] = rsqrtf(var + LN_EPS);
    }
    #pragma unroll
    for (int j = 0; j < 4; ++j) {
        const int col = n0 + j * 16 + l15;
        const float gg = g[col], bb = beta[col];
        #pragma unroll
        for (int r = 0; r < 4; ++r) {
            const int row = mr + lg * 4 + r;
            float res = (val[j][r] - mu_[r]) * rs_[r] * gg + bb;
            ln1[(size_t)row * CCH + col] = res;
            ln1b[(size_t)row * CCH + col] = (bf16)res;
        }
    }
}

// ---------------------------------------------------------------------------
// Fused FFN2 + residual + LN2 + output transpose, row-panel form (r15 proven).
// ---------------------------------------------------------------------------
__global__ __launch_bounds__(256)
void ffn2_ln2_t(const bf16* __restrict__ h1, const bf16* __restrict__ W2T,
                const float* __restrict__ bf2, const float* __restrict__ ln1,
                const float* __restrict__ g, const float* __restrict__ beta,
                float* __restrict__ out) {
    const int tid = threadIdx.x;
    const int w = tid >> 6, l = tid & 63;
    const int l15 = l & 15, lg = l >> 4;
    const int mr = blockIdx.x * 16;
    const int n0 = w * 64;

    f32x4 acc[4] = {};
    const bf16* a0 = &h1[(size_t)(mr + l15) * 1024 + lg * 8];
    const bf16* b0 = &W2T[(size_t)(n0 + l15) * 1024 + lg * 8];
    for (int k0 = 0; k0 < 1024; k0 += 32) {
        bf16x8 a = *reinterpret_cast<const bf16x8*>(a0 + k0);
        #pragma unroll
        for (int j = 0; j < 4; ++j) {
            bf16x8 b = *reinterpret_cast<const bf16x8*>(b0 + (size_t)j * 16 * 1024 + k0);
            acc[j] = __builtin_amdgcn_mfma_f32_16x16x32_bf16(a, b, acc[j], 0, 0, 0);
        }
    }

    float val[4][4];
    float rsum[4] = {0.f, 0.f, 0.f, 0.f}, rsq[4] = {0.f, 0.f, 0.f, 0.f};
    #pragma unroll
    for (int j = 0; j < 4; ++j) {
        const int col = n0 + j * 16 + l15;
        const float bs = bf2[col];
        #pragma unroll
        for (int r = 0; r < 4; ++r) {
            const int row = mr + lg * 4 + r;
            float v = acc[j][r] + bs + ln1[(size_t)row * CCH + col];
            val[j][r] = v;
            rsum[r] += v;
            rsq[r] += v * v;
        }
    }
    #pragma unroll
    for (int r = 0; r < 4; ++r) {
        #pragma unroll
        for (int off = 1; off < 16; off <<= 1) {
            rsum[r] += __shfl_xor(rsum[r], off);
            rsq[r]  += __shfl_xor(rsq[r], off);
        }
    }
    __shared__ float ssum[4][16], ssq[4][16];
    if (l15 == 0) {
        #pragma unroll
        for (int r = 0; r < 4; ++r) {
            ssum[w][lg * 4 + r] = rsum[r];
            ssq[w][lg * 4 + r]  = rsq[r];
        }
    }
    __syncthreads();
    float mu_[4], rs_[4];
    #pragma unroll
    for (int r = 0; r < 4; ++r) {
        const int row = lg * 4 + r;
        float s = (ssum[0][row] + ssum[1][row]) + (ssum[2][row] + ssum[3][row]);
        float q = (ssq[0][row] + ssq[1][row]) + (ssq[2][row] + ssq[3][row]);
        float mu = s * (1.0f / CCH);
        float var = q * (1.0f / CCH) - mu * mu;
        mu_[r] = mu;
        rs_[r] = rsqrtf(var + LN_EPS);
    }

    __shared__ float tile[256][17];
    #pragma unroll
    for (int j = 0; j < 4; ++j) {
        const int col = n0 + j * 16 + l15;
        const float gg = g[col], bb = beta[col];
        #pragma unroll
        for (int r = 0; r < 4; ++r)
            tile[col][lg * 4 + r] = (val[j][r] - mu_[r]) * rs_[r] * gg + bb;
    }
    __syncthreads();
    const int c = tid;
    float* orow = &out[(size_t)c * SQ + mr];
    #pragma unroll
    for (int q4 = 0; q4 < 4; ++q4) {
        float4 o4 = {tile[c][q4 * 4], tile[c][q4 * 4 + 1],
                     tile[c][q4 * 4 + 2], tile[c][q4 * 4 + 3]};
        *reinterpret_cast<float4*>(orow + q4 * 4) = o4;
    }
}

// ---------------------------------------------------------------------------
// MFMA flash attention v13 = r15's proven v11 pipeline (quad-Q, swapped QK^T,
// no-max softmax, LDS P relayout, K=32 PV, MFMA row-sum, v_exp) with
// NSPLIT=8: 1024 blocks = 4 blocks/CU = 4 waves/SIMD (2x TLP to hide the
// per-subtile serial chain).  NOTE r7/r16 both proved K=16 register PV is
// a regression (half-rate MFMA) -- keep K=32 + LDS relayout.
// ---------------------------------------------------------------------------
__global__ __launch_bounds__(256)
void flash_attn13(const bf16* __restrict__ qb, const bf16* __restrict__ kb,
                  const bf16* __restrict__ vT, bf16* __restrict__ Op,
                  float* __restrict__ Lp) {
    // grid (16, NH, 8) = 1024 blocks; 128 consecutive nids per XCD
    const int fid = blockIdx.x + 16 * (blockIdx.y + NH * blockIdx.z);
    const int nid = (fid & 7) * 128 + (fid >> 3);
    const int q0 = (nid & 15) * 256;
    const int h  = (nid >> 4) & 7;
    const int sp = nid >> 7;

    const int tid = threadIdx.x;
    const int w = tid >> 6, l = tid & 63;
    const int l15 = l & 15, lg = l >> 4;

    __shared__ unsigned int Sb[4][2][8][72];   // [wave][parity][slot][lane] 18KB

    bf16x8 aq[4];
    #pragma unroll
    for (int su = 0; su < 4; ++su)
        aq[su] = *reinterpret_cast<const bf16x8*>(
            &qb[(size_t)(q0 + su * 64 + w * 16 + l15) * CCH + h * HD + lg * 8]);

    f32x4 o[4][2] = {};
    f32x4 o2[4] = {};   // row-sum accumulators (ones-row MFMA)

    const bf16* kfrag = &kb[(size_t)l15 * CCH + h * HD + lg * 8];
    const bf16* vfrag = &vT[((size_t)h * VROWS + l15) * SQ + lg * 8];

    const int kt0 = sp * (SQ / NSPLIT / 64);
    const int kt1 = kt0 + (SQ / NSPLIT / 64);

    for (int kt = kt0; kt < kt1; ++kt) {
        const int kb0 = kt * 64;

        bf16x8 kf[4], vf[3][2];
        #pragma unroll
        for (int t = 0; t < 4; ++t)
            kf[t] = *reinterpret_cast<const bf16x8*>(kfrag + (size_t)(kb0 + t * 16) * CCH);
        #pragma unroll
        for (int dh = 0; dh < 3; ++dh)
            #pragma unroll
            for (int kh = 0; kh < 2; ++kh)
                vf[dh][kh] = *reinterpret_cast<const bf16x8*>(
                    vfrag + (size_t)dh * 16 * SQ + kb0 + kh * 32);

        #pragma unroll
        for (int su = 0; su < 4; ++su) {
            const int par = su & 1;
            f32x4 s[4];
            #pragma unroll
            for (int t = 0; t < 4; ++t)
                s[t] = __builtin_amdgcn_mfma_f32_16x16x32_bf16(
                    kf[t], aq[su], (f32x4){0.f, 0.f, 0.f, 0.f}, 0, 0, 0);

            #pragma unroll
            for (int t = 0; t < 4; ++t) {
                unsigned int u0 = __builtin_bit_cast(unsigned int, fast_exp2(s[t][0]));
                unsigned int u1 = __builtin_bit_cast(unsigned int, fast_exp2(s[t][1]));
                unsigned int u2 = __builtin_bit_cast(unsigned int, fast_exp2(s[t][2]));
                unsigned int u3 = __builtin_bit_cast(unsigned int, fast_exp2(s[t][3]));
                Sb[w][par][t * 2 + 0][l] = __builtin_amdgcn_perm(u1, u0, 0x07060302u);
                Sb[w][par][t * 2 + 1][l] = __builtin_amdgcn_perm(u3, u2, 0x07060302u);
            }

            #pragma unroll
            for (int kh = 0; kh < 2; ++kh) {
                const int sbase = kh * 4 + (lg >> 1) * 2;
                const int i0 = l15 + 16 * ((lg & 1) * 2);
                const int i1 = i0 + 16;
                union { unsigned int u[4]; bf16x8 v; } pb;
                pb.u[0] = Sb[w][par][sbase + 0][i0];
                pb.u[1] = Sb[w][par][sbase + 1][i0];
                pb.u[2] = Sb[w][par][sbase + 0][i1];
                pb.u[3] = Sb[w][par][sbase + 1][i1];
                #pragma unroll
                for (int dh = 0; dh < 2; ++dh)
                    o[su][dh] = __builtin_amdgcn_mfma_f32_16x16x32_bf16(
                        vf[dh][kh], pb.v, o[su][dh], 0, 0, 0);
                o2[su] = __builtin_amdgcn_mfma_f32_16x16x32_bf16(
                    vf[2][kh], pb.v, o2[su], 0, 0, 0);
            }
        }
    }

    const size_t obase = ((size_t)sp * NH + h) * HD;
    #pragma unroll
    for (int su = 0; su < 4; ++su) {
        const int qrow = q0 + su * 64 + w * 16 + l15;
        #pragma unroll
        for (int dh = 0; dh < 2; ++dh)
            #pragma unroll
            for (int r = 0; r < 4; ++r)
                Op[(obase + dh * 16 + lg * 4 + r) * SQ + qrow] = (bf16)o[su][dh][r];
        if (lg == 0)
            Lp[((size_t)sp * NH + h) * SQ + qrow] = o2[su][0];
    }
}

// ---------------------------------------------------------------------------
// Merge NSPLIT raw partial O^T [d][q] tiles -> atb [S][C] bf16.
// ---------------------------------------------------------------------------
__global__ __launch_bounds__(256)
void attn_merge3(const bf16* __restrict__ Op, const float* __restrict__ Lp,
                 bf16* __restrict__ atb) {
    const int h = blockIdx.y;
    const int q0 = blockIdx.x * 64;
    const int t = threadIdx.x;
    __shared__ float sInv[64];
    __shared__ float trans[32][65];

    if (t < 64) {
        float L = 0.f;
        #pragma unroll
        for (int sp = 0; sp < NSPLIT; ++sp)
            L += Lp[((size_t)sp * NH + h) * SQ + q0 + t];
        sInv[t] = 1.0f / L;
    }
    __syncthreads();

    const int q = t & 63, dg = t >> 6;
    float a[8] = {0.f, 0.f, 0.f, 0.f, 0.f, 0.f, 0.f, 0.f};
    for (int sp = 0; sp < NSPLIT; ++sp) {
        const size_t rb = ((size_t)sp * NH + h) * HD;
        #pragma unroll
        for (int i = 0; i < 8; ++i) {
            const int d = i * 4 + dg;
            a[i] += (float)Op[(rb + d) * SQ + q0 + q];
        }
    }
    const float invq = sInv[q];
    #pragma unroll
    for (int i = 0; i < 8; ++i)
        trans[i * 4 + dg][q] = a[i] * invq;
    __syncthreads();

    const int oq = t >> 2, od = (t & 3) * 8;
    bf16x8 o8;
    #pragma unroll
    for (int j = 0; j < 8; ++j) o8[j] = (bf16)trans[od + j][oq];
    *reinterpret_cast<bf16x8*>(&atb[(size_t)(q0 + oq) * CCH + h * HD + od]) = o8;
}

// ---------------------------------------------------------------------------
extern "C" void kernel_launch(void* const* d_in, const int* in_sizes, int n_in,
                              void* d_out, int out_size, void* d_ws, size_t ws_size,
                              hipStream_t stream) {
    const float* lidar = (const float*)d_in[0];
    const float* image = (const float*)d_in[1];
    const float* Wq  = (const float*)d_in[2];
    const float* bq  = (const float*)d_in[3];
    const float* Wk  = (const float*)d_in[4];
    const float* bk  = (const float*)d_in[5];
    const float* Wv  = (const float*)d_in[6];
    const float* bv  = (const float*)d_in[7];
    const float* Wo  = (const float*)d_in[8];
    const float* bo  = (const float*)d_in[9];
    const float* g1  = (const float*)d_in[10];
    const float* b1  = (const float*)d_in[11];
    const float* W1  = (const float*)d_in[12];
    const float* bf1 = (const float*)d_in[13];
    const float* W2  = (const float*)d_in[14];
    const float* bf2 = (const float*)d_in[15];
    const float* g2  = (const float*)d_in[16];
    const float* b2  = (const float*)d_in[17];
    float* out = (float*)d_out;

    // workspace layout (aliased; peak 23.75 MB).  Lp (1MB) in d_out until merge.
    char* ws = (char*)d_ws;
    const size_t KB = 1024;
    bf16* W2T = (bf16*)(ws + 0);                 // [0,512K)     live -> ffn2_ln2_t
    bf16* W1T = (bf16*)(ws + 512 * KB);          // [512K,1M)    live -> ffn1
    bf16* WoT = (bf16*)(ws + 1024 * KB);         // [1,1.125M)   live -> wo_ln1
    bf16* WqT = (bf16*)(ws + 1152 * KB);         // dead after qkv
    bf16* WkT = (bf16*)(ws + 1280 * KB);
    bf16* WvT = (bf16*)(ws + 1408 * KB);         // ends 1536K
    bf16* qb  = (bf16*)(ws + 1536 * KB);         // [1536K,3584K)  live -> wo_ln1
    bf16* kbb = (bf16*)(ws + 3584 * KB);         // [3584K,5632K)  dead after flash
    bf16* vTb = (bf16*)(ws + 5632 * KB);         // [5632K,7864K)  (33*8+15 rows) dead after flash
    bf16* xT  = (bf16*)(ws + 7936 * KB);         // [7936K,9984K)  dead after qkv
    bf16* yT  = (bf16*)(ws + 9984 * KB);         // [9984K,12032K) dead after qkv
    bf16* Op  = (bf16*)(ws + 7936 * KB);         // [7936K,24320K) 16MB, overlays xT/yT
    float* Lp = (float*)d_out;                   // 1MB scratch in d_out
    bf16* atb = (bf16*)(ws + 3584 * KB);         // reuses kbb; dead after wo_ln1
    float* ln1 = (float*)(ws + 7936 * KB);       // [7936K,12032K) reuses Op head; live -> ffn2
    bf16* ln1b = (bf16*)(ws + 5632 * KB);        // [5632K,7680K) reuses vTb; dead after ffn1
    bf16* h1  = (bf16*)(ws + 12032 * KB);        // [12032K,20224K) reuses Op tail

    // 1/sqrt(32) * log2(e) folded into K -> scores already in log2 domain
    const float qscale = 0.17677669529663687f * 1.4426950408889634f;
    dim3 blk(256);

    // all layout conversions in one launch
    cvt_all<<<dim3(2880), blk, 0, stream>>>(lidar, image, xT, yT,
                                            Wq, Wk, Wv, Wo, W1, W2,
                                            WqT, WkT, WvT, WoT, W1T, W2T, vTb);
    // fused QKV projections
    qkv_gemm<<<dim3(64, 4, 3), blk, 0, stream>>>(xT, yT, WqT, WkT, WvT,
                                                 bq, bk, bv, qb, kbb, vTb, qscale);
    // attention (split-KV x8, swapped-operand, no-max, MFMA row-sum, v_exp)
    flash_attn13<<<dim3(16, NH, NSPLIT), blk, 0, stream>>>(qb, kbb, vTb, Op, Lp);
    attn_merge3<<<dim3(SQ / 64, NH), blk, 0, stream>>>(Op, Lp, atb);
    // fused Wo projection + residual + LN1 (row-panel)
    wo_ln1<<<dim3(SQ / 16), blk, 0, stream>>>(atb, WoT, bo, qb, g1, b1, ln1, ln1b);
    // FFN1
    gemm_mfma<256, 2, true><<<dim3(64, 16), blk, 0, stream>>>(ln1b, W1T, bf1, nullptr, h1, 1024);
    // fused FFN2 + residual + LN2 + transpose (row-panel)
    ffn2_ln2_t<<<dim3(SQ / 16), blk, 0, stream>>>(h1, W2T, bf2, ln1, g2, b2, out);
}

// Round 18
// 125.526 us; speedup vs baseline: 1.1241x; 1.0096x over previous
//
#include <hip/hip_runtime.h>

#define SQ 4096      // sequence length = 64*64
#define CCH 256      // channels
#define NH 8         // heads
#define HD 32        // head dim
#define LN_EPS 1e-5f
#define NSPLIT 4     // kv splits per head
#define VROWS 48     // V^T rows per head: 32 data + 16 pad (row32=ones, rest 0)

typedef __bf16 bf16x8 __attribute__((ext_vector_type(8)));
typedef float f32x4 __attribute__((ext_vector_type(4)));
using bf16 = __bf16;

// Raw hardware 2^x (exp2f lowers to a ~20-VALU OCML guarded sequence;
// inputs here are bounded so the fixups are dead weight).
__device__ __forceinline__ float fast_exp2(float x) {
#if defined(__has_builtin)
#if __has_builtin(__builtin_amdgcn_exp2f)
    return __builtin_amdgcn_exp2f(x);
#else
    float r;
    asm("v_exp_f32 %0, %1" : "=v"(r) : "v"(x));
    return r;
#endif
#else
    float r;
    asm("v_exp_f32 %0, %1" : "=v"(r) : "v"(x));
    return r;
#endif
}

// ---------------------------------------------------------------------------
// Tile transpose + fp32->bf16 convert: src [R][Ccol] f32 -> dst [Ccol][R] bf16
// ---------------------------------------------------------------------------
__device__ __forceinline__ void tile_tc(const float* __restrict__ src, bf16* __restrict__ dst,
                                        int R, int Ccol, int ti, int tj) {
    __shared__ float t[32][33];
    const int tx = threadIdx.x & 31;
    const int ty = threadIdx.x >> 5;   // 0..7
    const int i0 = ti * 32, j0 = tj * 32;
    #pragma unroll
    for (int i = 0; i < 32; i += 8)
        t[ty + i][tx] = src[(size_t)(i0 + ty + i) * Ccol + j0 + tx];
    __syncthreads();
    #pragma unroll
    for (int i = 0; i < 32; i += 8)
        dst[(size_t)(j0 + ty + i) * R + i0 + tx] = (bf16)t[tx][ty + i];
}

// ---------------------------------------------------------------------------
// ALL conversions in one launch (2880 blocks).
// ---------------------------------------------------------------------------
__global__ __launch_bounds__(256)
void cvt_all(const float* __restrict__ x, const float* __restrict__ y,
             bf16* __restrict__ xT, bf16* __restrict__ yT,
             const float* Wq, const float* Wk, const float* Wv, const float* Wo,
             const float* W1, const float* W2,
             bf16* WqT, bf16* WkT, bf16* WvT, bf16* WoT, bf16* W1T, bf16* W2T,
             bf16* vTb) {
    const int id = blockIdx.x;
    if (id < 2048) {
        const int z = id >> 10;
        const int t = id & 1023;
        const float* s = z ? y : x;
        bf16* d = z ? yT : xT;
        tile_tc(s, d, CCH, SQ, t >> 7, t & 127);
        return;
    }
    const int wid = id - 2048;
    if (wid < 256) {
        const int w = wid >> 6, local = wid & 63;
        const float* s = (w == 0) ? Wq : (w == 1) ? Wk : (w == 2) ? Wv : Wo;
        bf16* d = (w == 0) ? WqT : (w == 1) ? WkT : (w == 2) ? WvT : WoT;
        tile_tc(s, d, 256, 256, local >> 3, local & 7);
    } else if (wid < 512) {
        const int local = wid - 256;
        tile_tc(W1, W1T, 256, 1024, local >> 5, local & 31);
    } else if (wid < 768) {
        const int local = wid - 512;
        tile_tc(W2, W2T, 1024, 256, local >> 3, local & 7);
    } else {
        // init vT pad rows: per head rows 32..47 -> row 32 = 1.0, rest 0
        const int local = wid - 768;         // 0..63
        #pragma unroll
        for (int rr = 0; rr < 2; ++rr) {
            const int pr = local * 2 + rr;   // 0..127
            const int hh = pr >> 4, j = pr & 15;
            const bf16 val = (bf16)((j == 0) ? 1.0f : 0.0f);
            bf16x8 v8;
            #pragma unroll
            for (int e = 0; e < 8; ++e) v8[e] = val;
            bf16* dst = vTb + ((size_t)hh * VROWS + 32 + j) * SQ + threadIdx.x * 16;
            *reinterpret_cast<bf16x8*>(dst) = v8;
            *reinterpret_cast<bf16x8*>(dst + 8) = v8;
        }
    }
}

// ---------------------------------------------------------------------------
// 4-wave MFMA GEMM: 64x64 tile, wave -> 32x32, reg fragments.
// OUT_MODE: 0 = f32; 2 = bf16.
// ---------------------------------------------------------------------------
template <int K, int OUT_MODE, bool RELU>
__global__ __launch_bounds__(256)
void gemm_mfma(const bf16* __restrict__ A, const bf16* __restrict__ BT,
               const float* __restrict__ bias, float* __restrict__ Cf,
               bf16* __restrict__ Cb, int N) {
    const int tid = threadIdx.x;
    const int w = tid >> 6, l = tid & 63;
    const int l15 = l & 15, lg = l >> 4;
    const int m0 = blockIdx.x * 64 + (w >> 1) * 32;
    const int n0 = blockIdx.y * 64 + (w & 1) * 32;

    f32x4 acc[2][2] = {};
    const bf16* a0 = &A[(size_t)(m0 + l15) * K + lg * 8];
    const bf16* b0 = &BT[(size_t)(n0 + l15) * K + lg * 8];

    for (int k0 = 0; k0 < K; k0 += 32) {
        bf16x8 a[2], b[2];
        a[0] = *reinterpret_cast<const bf16x8*>(a0 + k0);
        a[1] = *reinterpret_cast<const bf16x8*>(a0 + (size_t)16 * K + k0);
        b[0] = *reinterpret_cast<const bf16x8*>(b0 + k0);
        b[1] = *reinterpret_cast<const bf16x8*>(b0 + (size_t)16 * K + k0);
        #pragma unroll
        for (int i = 0; i < 2; ++i)
            #pragma unroll
            for (int j = 0; j < 2; ++j)
                acc[i][j] = __builtin_amdgcn_mfma_f32_16x16x32_bf16(a[i], b[j], acc[i][j], 0, 0, 0);
    }

    #pragma unroll
    for (int i = 0; i < 2; ++i) {
        #pragma unroll
        for (int j = 0; j < 2; ++j) {
            const int col = n0 + j * 16 + l15;
            const float bs = bias[col];
            #pragma unroll
            for (int r = 0; r < 4; ++r) {
                const int row = m0 + i * 16 + lg * 4 + r;
                float val = acc[i][j][r] + bs;
                if (RELU) val = fmaxf(val, 0.f);
                if constexpr (OUT_MODE == 0)
                    Cf[(size_t)row * N + col] = val;
                if constexpr (OUT_MODE == 2)
                    Cb[(size_t)row * N + col] = (bf16)val;
            }
        }
    }
}

// ---------------------------------------------------------------------------
// 4-wave fused QKV projections: grid z = 0(q) / 1(k) / 2(v).
// ---------------------------------------------------------------------------
__global__ __launch_bounds__(256)
void qkv_gemm(const bf16* __restrict__ xT, const bf16* __restrict__ yT,
              const bf16* __restrict__ WqT, const bf16* __restrict__ WkT,
              const bf16* __restrict__ WvT,
              const float* __restrict__ bq, const float* __restrict__ bk,
              const float* __restrict__ bv,
              bf16* __restrict__ qb, bf16* __restrict__ kbb, bf16* __restrict__ vTb,
              float kscale) {
    const int z = blockIdx.z;
    const bf16* A  = (z == 0) ? xT : yT;
    const bf16* BT = (z == 0) ? WqT : (z == 1) ? WkT : WvT;
    const float* bias = (z == 0) ? bq : (z == 1) ? bk : bv;

    const int tid = threadIdx.x;
    const int w = tid >> 6, l = tid & 63;
    const int l15 = l & 15, lg = l >> 4;
    const int m0 = blockIdx.x * 64 + (w >> 1) * 32;
    const int n0 = blockIdx.y * 64 + (w & 1) * 32;

    f32x4 acc[2][2] = {};
    const bf16* a0 = &A[(size_t)(m0 + l15) * CCH + lg * 8];
    const bf16* b0 = &BT[(size_t)(n0 + l15) * CCH + lg * 8];

    for (int k0 = 0; k0 < CCH; k0 += 32) {
        bf16x8 a[2], b[2];
        a[0] = *reinterpret_cast<const bf16x8*>(a0 + k0);
        a[1] = *reinterpret_cast<const bf16x8*>(a0 + (size_t)16 * CCH + k0);
        b[0] = *reinterpret_cast<const bf16x8*>(b0 + k0);
        b[1] = *reinterpret_cast<const bf16x8*>(b0 + (size_t)16 * CCH + k0);
        #pragma unroll
        for (int i = 0; i < 2; ++i)
            #pragma unroll
            for (int j = 0; j < 2; ++j)
                acc[i][j] = __builtin_amdgcn_mfma_f32_16x16x32_bf16(a[i], b[j], acc[i][j], 0, 0, 0);
    }

    const float sc = (z == 1) ? kscale : 1.f;
    #pragma unroll
    for (int i = 0; i < 2; ++i) {
        #pragma unroll
        for (int j = 0; j < 2; ++j) {
            const int col = n0 + j * 16 + l15;
            const float bs = bias[col];
            #pragma unroll
            for (int r = 0; r < 4; ++r) {
                const int row = m0 + i * 16 + lg * 4 + r;
                float val = acc[i][j][r] + bs;
                if (z == 2)
                    vTb[((size_t)(col >> 5) * VROWS + (col & 31)) * SQ + row] = (bf16)val;
                else if (z == 1)
                    kbb[(size_t)row * CCH + col] = (bf16)(val * sc);
                else
                    qb[(size_t)row * CCH + col] = (bf16)val;
            }
        }
    }
}

// ---------------------------------------------------------------------------
// Fused Wo projection + residual + LN1, row-panel, 8 WAVES (512 threads):
// wave w -> 32-col panel.  B-traffic per block unchanged; 2x waves/SIMD.
// Output bf16 only (LN2 residual reads bf16 too).
// ---------------------------------------------------------------------------
__global__ __launch_bounds__(512)
void wo_ln1(const bf16* __restrict__ atb, const bf16* __restrict__ WoT,
            const float* __restrict__ bo, const bf16* __restrict__ qb,
            const float* __restrict__ g, const float* __restrict__ beta,
            bf16* __restrict__ ln1b) {
    const int tid = threadIdx.x;
    const int w = tid >> 6, l = tid & 63;
    const int l15 = l & 15, lg = l >> 4;
    const int mr = blockIdx.x * 16;
    const int n0 = w * 32;

    f32x4 acc[2] = {};
    const bf16* a0 = &atb[(size_t)(mr + l15) * CCH + lg * 8];
    const bf16* b0 = &WoT[(size_t)(n0 + l15) * CCH + lg * 8];
    #pragma unroll
    for (int k0 = 0; k0 < CCH; k0 += 32) {
        bf16x8 a = *reinterpret_cast<const bf16x8*>(a0 + k0);
        #pragma unroll
        for (int j = 0; j < 2; ++j) {
            bf16x8 b = *reinterpret_cast<const bf16x8*>(b0 + (size_t)j * 16 * CCH + k0);
            acc[j] = __builtin_amdgcn_mfma_f32_16x16x32_bf16(a, b, acc[j], 0, 0, 0);
        }
    }

    float val[2][4];
    float rsum[4] = {0.f, 0.f, 0.f, 0.f}, rsq[4] = {0.f, 0.f, 0.f, 0.f};
    #pragma unroll
    for (int j = 0; j < 2; ++j) {
        const int col = n0 + j * 16 + l15;
        const float bs = bo[col];
        #pragma unroll
        for (int r = 0; r < 4; ++r) {
            const int row = mr + lg * 4 + r;
            float v = acc[j][r] + bs + (float)qb[(size_t)row * CCH + col];
            val[j][r] = v;
            rsum[r] += v;
            rsq[r] += v * v;
        }
    }
    #pragma unroll
    for (int r = 0; r < 4; ++r) {
        #pragma unroll
        for (int off = 1; off < 16; off <<= 1) {
            rsum[r] += __shfl_xor(rsum[r], off);
            rsq[r]  += __shfl_xor(rsq[r], off);
        }
    }
    __shared__ float ssum[8][16], ssq[8][16];
    if (l15 == 0) {
        #pragma unroll
        for (int r = 0; r < 4; ++r) {
            ssum[w][lg * 4 + r] = rsum[r];
            ssq[w][lg * 4 + r]  = rsq[r];
        }
    }
    __syncthreads();
    float mu_[4], rs_[4];
    #pragma unroll
    for (int r = 0; r < 4; ++r) {
        const int row = lg * 4 + r;
        float s = 0.f, q = 0.f;
        #pragma unroll
        for (int ww = 0; ww < 8; ++ww) { s += ssum[ww][row]; q += ssq[ww][row]; }
        float mu = s * (1.0f / CCH);
        float var = q * (1.0f / CCH) - mu * mu;
        mu_[r] = mu;
        rs_[r] = rsqrtf(var + LN_EPS);
    }
    #pragma unroll
    for (int j = 0; j < 2; ++j) {
        const int col = n0 + j * 16 + l15;
        const float gg = g[col], bb = beta[col];
        #pragma unroll
        for (int r = 0; r < 4; ++r) {
            const int row = mr + lg * 4 + r;
            ln1b[(size_t)row * CCH + col] = (bf16)((val[j][r] - mu_[r]) * rs_[r] * gg + bb);
        }
    }
}

// ---------------------------------------------------------------------------
// Fused FFN2 + residual(bf16) + LN2 + output transpose, 8 WAVES (512 thr):
// wave w -> 32-col panel, K=1024.  Transpose via [256][17] LDS tile.
// ---------------------------------------------------------------------------
__global__ __launch_bounds__(512)
void ffn2_ln2_t(const bf16* __restrict__ h1, const bf16* __restrict__ W2T,
                const float* __restrict__ bf2, const bf16* __restrict__ ln1b,
                const float* __restrict__ g, const float* __restrict__ beta,
                float* __restrict__ out) {
    const int tid = threadIdx.x;
    const int w = tid >> 6, l = tid & 63;
    const int l15 = l & 15, lg = l >> 4;
    const int mr = blockIdx.x * 16;
    const int n0 = w * 32;

    f32x4 acc[2] = {};
    const bf16* a0 = &h1[(size_t)(mr + l15) * 1024 + lg * 8];
    const bf16* b0 = &W2T[(size_t)(n0 + l15) * 1024 + lg * 8];
    for (int k0 = 0; k0 < 1024; k0 += 32) {
        bf16x8 a = *reinterpret_cast<const bf16x8*>(a0 + k0);
        #pragma unroll
        for (int j = 0; j < 2; ++j) {
            bf16x8 b = *reinterpret_cast<const bf16x8*>(b0 + (size_t)j * 16 * 1024 + k0);
            acc[j] = __builtin_amdgcn_mfma_f32_16x16x32_bf16(a, b, acc[j], 0, 0, 0);
        }
    }

    float val[2][4];
    float rsum[4] = {0.f, 0.f, 0.f, 0.f}, rsq[4] = {0.f, 0.f, 0.f, 0.f};
    #pragma unroll
    for (int j = 0; j < 2; ++j) {
        const int col = n0 + j * 16 + l15;
        const float bs = bf2[col];
        #pragma unroll
        for (int r = 0; r < 4; ++r) {
            const int row = mr + lg * 4 + r;
            float v = acc[j][r] + bs + (float)ln1b[(size_t)row * CCH + col];
            val[j][r] = v;
            rsum[r] += v;
            rsq[r] += v * v;
        }
    }
    #pragma unroll
    for (int r = 0; r < 4; ++r) {
        #pragma unroll
        for (int off = 1; off < 16; off <<= 1) {
            rsum[r] += __shfl_xor(rsum[r], off);
            rsq[r]  += __shfl_xor(rsq[r], off);
        }
    }
    __shared__ float ssum[8][16], ssq[8][16];
    if (l15 == 0) {
        #pragma unroll
        for (int r = 0; r < 4; ++r) {
            ssum[w][lg * 4 + r] = rsum[r];
            ssq[w][lg * 4 + r]  = rsq[r];
        }
    }
    __syncthreads();
    float mu_[4], rs_[4];
    #pragma unroll
    for (int r = 0; r < 4; ++r) {
        const int row = lg * 4 + r;
        float s = 0.f, q = 0.f;
        #pragma unroll
        for (int ww = 0; ww < 8; ++ww) { s += ssum[ww][row]; q += ssq[ww][row]; }
        float mu = s * (1.0f / CCH);
        float var = q * (1.0f / CCH) - mu * mu;
        mu_[r] = mu;
        rs_[r] = rsqrtf(var + LN_EPS);
    }

    __shared__ float tile[256][17];
    #pragma unroll
    for (int j = 0; j < 2; ++j) {
        const int col = n0 + j * 16 + l15;
        const float gg = g[col], bb = beta[col];
        #pragma unroll
        for (int r = 0; r < 4; ++r)
            tile[col][lg * 4 + r] = (val[j][r] - mu_[r]) * rs_[r] * gg + bb;
    }
    __syncthreads();
    // 512 threads: c = tid&255, row-half rh = tid>>8 -> 8 rows each
    const int c = tid & 255, rh = tid >> 8;
    float* orow = &out[(size_t)c * SQ + mr + rh * 8];
    #pragma unroll
    for (int q4 = 0; q4 < 2; ++q4) {
        const int rbase = rh * 8 + q4 * 4;
        float4 o4 = {tile[c][rbase], tile[c][rbase + 1],
                     tile[c][rbase + 2], tile[c][rbase + 3]};
        *reinterpret_cast<float4*>(orow + q4 * 4) = o4;
    }
}

// ---------------------------------------------------------------------------
// MFMA flash attention v11 (r15 exact): quad-Q, swapped QK^T, no-max softmax,
// LDS P relayout, K=32 PV, MFMA row-sum via ones-row, raw v_exp_f32.
// NSPLIT=4 (r17 proved NSPLIT=8 is a net loss: no occupancy gain, more fetch).
// ---------------------------------------------------------------------------
__global__ __launch_bounds__(256)
void flash_attn11(const bf16* __restrict__ qb, const bf16* __restrict__ kb,
                  const bf16* __restrict__ vT, bf16* __restrict__ Op,
                  float* __restrict__ Lp) {
    const int fid = blockIdx.x + 16 * (blockIdx.y + NH * blockIdx.z);
    const int nid = (fid & 7) * 64 + (fid >> 3);
    const int q0 = (nid & 15) * 256;
    const int h  = (nid >> 4) & 7;
    const int sp = nid >> 7;

    const int tid = threadIdx.x;
    const int w = tid >> 6, l = tid & 63;
    const int l15 = l & 15, lg = l >> 4;

    __shared__ unsigned int Sb[4][2][8][72];   // [wave][parity][slot][lane] 18KB

    bf16x8 aq[4];
    #pragma unroll
    for (int su = 0; su < 4; ++su)
        aq[su] = *reinterpret_cast<const bf16x8*>(
            &qb[(size_t)(q0 + su * 64 + w * 16 + l15) * CCH + h * HD + lg * 8]);

    f32x4 o[4][2] = {};
    f32x4 o2[4] = {};   // row-sum accumulators (ones-row MFMA)

    const bf16* kfrag = &kb[(size_t)l15 * CCH + h * HD + lg * 8];
    const bf16* vfrag = &vT[((size_t)h * VROWS + l15) * SQ + lg * 8];

    const int kt0 = sp * (SQ / NSPLIT / 64);
    const int kt1 = kt0 + (SQ / NSPLIT / 64);

    for (int kt = kt0; kt < kt1; ++kt) {
        const int kb0 = kt * 64;

        bf16x8 kf[4], vf[3][2];
        #pragma unroll
        for (int t = 0; t < 4; ++t)
            kf[t] = *reinterpret_cast<const bf16x8*>(kfrag + (size_t)(kb0 + t * 16) * CCH);
        #pragma unroll
        for (int dh = 0; dh < 3; ++dh)
            #pragma unroll
            for (int kh = 0; kh < 2; ++kh)
                vf[dh][kh] = *reinterpret_cast<const bf16x8*>(
                    vfrag + (size_t)dh * 16 * SQ + kb0 + kh * 32);

        #pragma unroll
        for (int su = 0; su < 4; ++su) {
            const int par = su & 1;
            f32x4 s[4];
            #pragma unroll
            for (int t = 0; t < 4; ++t)
                s[t] = __builtin_amdgcn_mfma_f32_16x16x32_bf16(
                    kf[t], aq[su], (f32x4){0.f, 0.f, 0.f, 0.f}, 0, 0, 0);

            #pragma unroll
            for (int t = 0; t < 4; ++t) {
                unsigned int u0 = __builtin_bit_cast(unsigned int, fast_exp2(s[t][0]));
                unsigned int u1 = __builtin_bit_cast(unsigned int, fast_exp2(s[t][1]));
                unsigned int u2 = __builtin_bit_cast(unsigned int, fast_exp2(s[t][2]));
                unsigned int u3 = __builtin_bit_cast(unsigned int, fast_exp2(s[t][3]));
                Sb[w][par][t * 2 + 0][l] = __builtin_amdgcn_perm(u1, u0, 0x07060302u);
                Sb[w][par][t * 2 + 1][l] = __builtin_amdgcn_perm(u3, u2, 0x07060302u);
            }

            #pragma unroll
            for (int kh = 0; kh < 2; ++kh) {
                const int sbase = kh * 4 + (lg >> 1) * 2;
                const int i0 = l15 + 16 * ((lg & 1) * 2);
                const int i1 = i0 + 16;
                union { unsigned int u[4]; bf16x8 v; } pb;
                pb.u[0] = Sb[w][par][sbase + 0][i0];
                pb.u[1] = Sb[w][par][sbase + 1][i0];
                pb.u[2] = Sb[w][par][sbase + 0][i1];
                pb.u[3] = Sb[w][par][sbase + 1][i1];
                #pragma unroll
                for (int dh = 0; dh < 2; ++dh)
                    o[su][dh] = __builtin_amdgcn_mfma_f32_16x16x32_bf16(
                        vf[dh][kh], pb.v, o[su][dh], 0, 0, 0);
                o2[su] = __builtin_amdgcn_mfma_f32_16x16x32_bf16(
                    vf[2][kh], pb.v, o2[su], 0, 0, 0);
            }
        }
    }

    const size_t obase = ((size_t)sp * NH + h) * HD;
    #pragma unroll
    for (int su = 0; su < 4; ++su) {
        const int qrow = q0 + su * 64 + w * 16 + l15;
        #pragma unroll
        for (int dh = 0; dh < 2; ++dh)
            #pragma unroll
            for (int r = 0; r < 4; ++r)
                Op[(obase + dh * 16 + lg * 4 + r) * SQ + qrow] = (bf16)o[su][dh][r];
        if (lg == 0)
            Lp[((size_t)sp * NH + h) * SQ + qrow] = o2[su][0];
    }
}

// ---------------------------------------------------------------------------
// Merge NSPLIT raw partial O^T [d][q] tiles -> atb [S][C] bf16.
// ---------------------------------------------------------------------------
__global__ __launch_bounds__(256)
void attn_merge3(const bf16* __restrict__ Op, const float* __restrict__ Lp,
                 bf16* __restrict__ atb) {
    const int h = blockIdx.y;
    const int q0 = blockIdx.x * 64;
    const int t = threadIdx.x;
    __shared__ float sInv[64];
    __shared__ float trans[32][65];

    if (t < 64) {
        float L = 0.f;
        #pragma unroll
        for (int sp = 0; sp < NSPLIT; ++sp)
            L += Lp[((size_t)sp * NH + h) * SQ + q0 + t];
        sInv[t] = 1.0f / L;
    }
    __syncthreads();

    const int q = t & 63, dg = t >> 6;
    float a[8] = {0.f, 0.f, 0.f, 0.f, 0.f, 0.f, 0.f, 0.f};
    for (int sp = 0; sp < NSPLIT; ++sp) {
        const size_t rb = ((size_t)sp * NH + h) * HD;
        #pragma unroll
        for (int i = 0; i < 8; ++i) {
            const int d = i * 4 + dg;
            a[i] += (float)Op[(rb + d) * SQ + q0 + q];
        }
    }
    const float invq = sInv[q];
    #pragma unroll
    for (int i = 0; i < 8; ++i)
        trans[i * 4 + dg][q] = a[i] * invq;
    __syncthreads();

    const int oq = t >> 2, od = (t & 3) * 8;
    bf16x8 o8;
    #pragma unroll
    for (int j = 0; j < 8; ++j) o8[j] = (bf16)trans[od + j][oq];
    *reinterpret_cast<bf16x8*>(&atb[(size_t)(q0 + oq) * CCH + h * HD + od]) = o8;
}

// ---------------------------------------------------------------------------
extern "C" void kernel_launch(void* const* d_in, const int* in_sizes, int n_in,
                              void* d_out, int out_size, void* d_ws, size_t ws_size,
                              hipStream_t stream) {
    const float* lidar = (const float*)d_in[0];
    const float* image = (const float*)d_in[1];
    const float* Wq  = (const float*)d_in[2];
    const float* bq  = (const float*)d_in[3];
    const float* Wk  = (const float*)d_in[4];
    const float* bk  = (const float*)d_in[5];
    const float* Wv  = (const float*)d_in[6];
    const float* bv  = (const float*)d_in[7];
    const float* Wo  = (const float*)d_in[8];
    const float* bo  = (const float*)d_in[9];
    const float* g1  = (const float*)d_in[10];
    const float* b1  = (const float*)d_in[11];
    const float* W1  = (const float*)d_in[12];
    const float* bf1 = (const float*)d_in[13];
    const float* W2  = (const float*)d_in[14];
    const float* bf2 = (const float*)d_in[15];
    const float* g2  = (const float*)d_in[16];
    const float* b2  = (const float*)d_in[17];
    float* out = (float*)d_out;

    // workspace layout (aliased; peak 23.5 MB).  Lp (512K) in d_out until merge.
    char* ws = (char*)d_ws;
    const size_t KB = 1024;
    bf16* W2T = (bf16*)(ws + 0);                 // [0,512K)     live -> ffn2_ln2_t
    bf16* W1T = (bf16*)(ws + 512 * KB);          // [512K,1M)    live -> ffn1
    bf16* WoT = (bf16*)(ws + 1024 * KB);         // [1,1.125M)   live -> wo_ln1
    bf16* WqT = (bf16*)(ws + 1152 * KB);         // dead after qkv
    bf16* WkT = (bf16*)(ws + 1280 * KB);
    bf16* WvT = (bf16*)(ws + 1408 * KB);         // ends 1.5M
    bf16* qb  = (bf16*)(ws + 1536 * KB);         // [1.5,3.5M)   live -> wo_ln1
    bf16* kbb = (bf16*)(ws + 3584 * KB);         // [3.5,5.5M)   dead after flash
    bf16* vTb = (bf16*)(ws + 5632 * KB);         // [5.5,8.5M)   padded; dead after flash
    bf16* xT  = (bf16*)(ws + 8704 * KB);         // [8.5,10.5M)  dead after qkv
    bf16* yT  = (bf16*)(ws + 10752 * KB);        // [10.5,12.5M) dead after qkv
    bf16* Op  = (bf16*)(ws + 8704 * KB);         // [8.5,16.5M)  overlays xT/yT
    float* Lp = (float*)d_out;                   // 512K scratch in d_out
    bf16* atb = (bf16*)(ws + 3584 * KB);         // reuses kbb; dead after wo_ln1
    bf16* ln1b = (bf16*)(ws + 5632 * KB);        // [5.5,7.5M)   reuses vTb; live -> ffn2
    bf16* h1  = (bf16*)(ws + 9728 * KB);         // [9.5,17.5M)  dead after ffn2_ln2_t

    // 1/sqrt(32) * log2(e) folded into K -> scores already in log2 domain
    const float qscale = 0.17677669529663687f * 1.4426950408889634f;
    dim3 blk(256), blk8(512);

    // all layout conversions in one launch
    cvt_all<<<dim3(2880), blk, 0, stream>>>(lidar, image, xT, yT,
                                            Wq, Wk, Wv, Wo, W1, W2,
                                            WqT, WkT, WvT, WoT, W1T, W2T, vTb);
    // fused QKV projections
    qkv_gemm<<<dim3(64, 4, 3), blk, 0, stream>>>(xT, yT, WqT, WkT, WvT,
                                                 bq, bk, bv, qb, kbb, vTb, qscale);
    // attention (split-KV x4, swapped-operand, no-max, MFMA row-sum, v_exp)
    flash_attn11<<<dim3(16, NH, NSPLIT), blk, 0, stream>>>(qb, kbb, vTb, Op, Lp);
    attn_merge3<<<dim3(SQ / 64, NH), blk, 0, stream>>>(Op, Lp, atb);
    // fused Wo projection + residual + LN1 (row-panel, 8 waves)
    wo_ln1<<<dim3(SQ / 16), blk8, 0, stream>>>(atb, WoT, bo, qb, g1, b1, ln1b);
    // FFN1
    gemm_mfma<256, 2, true><<<dim3(64, 16), blk, 0, stream>>>(ln1b, W1T, bf1, nullptr, h1, 1024);
    // fused FFN2 + residual(bf16) + LN2 + transpose (row-panel, 8 waves)
    ffn2_ln2_t<<<dim3(SQ / 16), blk8, 0, stream>>>(h1, W2T, bf2, ln1b, g2, b2, out);
}

// Round 19
// 119.939 us; speedup vs baseline: 1.1764x; 1.0466x over previous
//
#include <hip/hip_runtime.h>

#define SQ 4096      // sequence length = 64*64
#define CCH 256      // channels
#define NH 8         // heads
#define HD 32        // head dim
#define LN_EPS 1e-5f
#define NSPLIT 4     // kv splits per head
#define VROWS 48     // V^T rows per head: 32 data + 16 pad (row32=ones, rest 0)

typedef __bf16 bf16x8 __attribute__((ext_vector_type(8)));
typedef float f32x4 __attribute__((ext_vector_type(4)));
using bf16 = __bf16;

// Raw hardware 2^x (exp2f lowers to a ~20-VALU OCML guarded sequence;
// inputs here are bounded so the fixups are dead weight).
__device__ __forceinline__ float fast_exp2(float x) {
#if defined(__has_builtin)
#if __has_builtin(__builtin_amdgcn_exp2f)
    return __builtin_amdgcn_exp2f(x);
#else
    float r;
    asm("v_exp_f32 %0, %1" : "=v"(r) : "v"(x));
    return r;
#endif
#else
    float r;
    asm("v_exp_f32 %0, %1" : "=v"(r) : "v"(x));
    return r;
#endif
}

// ---------------------------------------------------------------------------
// Tile transpose + fp32->bf16 convert: src [R][Ccol] f32 -> dst [Ccol][R] bf16
// ---------------------------------------------------------------------------
__device__ __forceinline__ void tile_tc(const float* __restrict__ src, bf16* __restrict__ dst,
                                        int R, int Ccol, int ti, int tj) {
    __shared__ float t[32][33];
    const int tx = threadIdx.x & 31;
    const int ty = threadIdx.x >> 5;   // 0..7
    const int i0 = ti * 32, j0 = tj * 32;
    #pragma unroll
    for (int i = 0; i < 32; i += 8)
        t[ty + i][tx] = src[(size_t)(i0 + ty + i) * Ccol + j0 + tx];
    __syncthreads();
    #pragma unroll
    for (int i = 0; i < 32; i += 8)
        dst[(size_t)(j0 + ty + i) * R + i0 + tx] = (bf16)t[tx][ty + i];
}

// ---------------------------------------------------------------------------
// ALL conversions in one launch (2880 blocks).
// ---------------------------------------------------------------------------
__global__ __launch_bounds__(256)
void cvt_all(const float* __restrict__ x, const float* __restrict__ y,
             bf16* __restrict__ xT, bf16* __restrict__ yT,
             const float* Wq, const float* Wk, const float* Wv, const float* Wo,
             const float* W1, const float* W2,
             bf16* WqT, bf16* WkT, bf16* WvT, bf16* WoT, bf16* W1T, bf16* W2T,
             bf16* vTb) {
    const int id = blockIdx.x;
    if (id < 2048) {
        const int z = id >> 10;
        const int t = id & 1023;
        const float* s = z ? y : x;
        bf16* d = z ? yT : xT;
        tile_tc(s, d, CCH, SQ, t >> 7, t & 127);
        return;
    }
    const int wid = id - 2048;
    if (wid < 256) {
        const int w = wid >> 6, local = wid & 63;
        const float* s = (w == 0) ? Wq : (w == 1) ? Wk : (w == 2) ? Wv : Wo;
        bf16* d = (w == 0) ? WqT : (w == 1) ? WkT : (w == 2) ? WvT : WoT;
        tile_tc(s, d, 256, 256, local >> 3, local & 7);
    } else if (wid < 512) {
        const int local = wid - 256;
        tile_tc(W1, W1T, 256, 1024, local >> 5, local & 31);
    } else if (wid < 768) {
        const int local = wid - 512;
        tile_tc(W2, W2T, 1024, 256, local >> 3, local & 7);
    } else {
        // init vT pad rows: per head rows 32..47 -> row 32 = 1.0, rest 0
        const int local = wid - 768;         // 0..63
        #pragma unroll
        for (int rr = 0; rr < 2; ++rr) {
            const int pr = local * 2 + rr;   // 0..127
            const int hh = pr >> 4, j = pr & 15;
            const bf16 val = (bf16)((j == 0) ? 1.0f : 0.0f);
            bf16x8 v8;
            #pragma unroll
            for (int e = 0; e < 8; ++e) v8[e] = val;
            bf16* dst = vTb + ((size_t)hh * VROWS + 32 + j) * SQ + threadIdx.x * 16;
            *reinterpret_cast<bf16x8*>(dst) = v8;
            *reinterpret_cast<bf16x8*>(dst + 8) = v8;
        }
    }
}

// ---------------------------------------------------------------------------
// 4-wave MFMA GEMM: 64x64 tile, wave -> 32x32, reg fragments.
// OUT_MODE: 0 = f32; 2 = bf16.
// ---------------------------------------------------------------------------
template <int K, int OUT_MODE, bool RELU>
__global__ __launch_bounds__(256)
void gemm_mfma(const bf16* __restrict__ A, const bf16* __restrict__ BT,
               const float* __restrict__ bias, float* __restrict__ Cf,
               bf16* __restrict__ Cb, int N) {
    const int tid = threadIdx.x;
    const int w = tid >> 6, l = tid & 63;
    const int l15 = l & 15, lg = l >> 4;
    const int m0 = blockIdx.x * 64 + (w >> 1) * 32;
    const int n0 = blockIdx.y * 64 + (w & 1) * 32;

    f32x4 acc[2][2] = {};
    const bf16* a0 = &A[(size_t)(m0 + l15) * K + lg * 8];
    const bf16* b0 = &BT[(size_t)(n0 + l15) * K + lg * 8];

    for (int k0 = 0; k0 < K; k0 += 32) {
        bf16x8 a[2], b[2];
        a[0] = *reinterpret_cast<const bf16x8*>(a0 + k0);
        a[1] = *reinterpret_cast<const bf16x8*>(a0 + (size_t)16 * K + k0);
        b[0] = *reinterpret_cast<const bf16x8*>(b0 + k0);
        b[1] = *reinterpret_cast<const bf16x8*>(b0 + (size_t)16 * K + k0);
        #pragma unroll
        for (int i = 0; i < 2; ++i)
            #pragma unroll
            for (int j = 0; j < 2; ++j)
                acc[i][j] = __builtin_amdgcn_mfma_f32_16x16x32_bf16(a[i], b[j], acc[i][j], 0, 0, 0);
    }

    #pragma unroll
    for (int i = 0; i < 2; ++i) {
        #pragma unroll
        for (int j = 0; j < 2; ++j) {
            const int col = n0 + j * 16 + l15;
            const float bs = bias[col];
            #pragma unroll
            for (int r = 0; r < 4; ++r) {
                const int row = m0 + i * 16 + lg * 4 + r;
                float val = acc[i][j][r] + bs;
                if (RELU) val = fmaxf(val, 0.f);
                if constexpr (OUT_MODE == 0)
                    Cf[(size_t)row * N + col] = val;
                if constexpr (OUT_MODE == 2)
                    Cb[(size_t)row * N + col] = (bf16)val;
            }
        }
    }
}

// ---------------------------------------------------------------------------
// 4-wave fused QKV projections: grid z = 0(q) / 1(k) / 2(v).
// ---------------------------------------------------------------------------
__global__ __launch_bounds__(256)
void qkv_gemm(const bf16* __restrict__ xT, const bf16* __restrict__ yT,
              const bf16* __restrict__ WqT, const bf16* __restrict__ WkT,
              const bf16* __restrict__ WvT,
              const float* __restrict__ bq, const float* __restrict__ bk,
              const float* __restrict__ bv,
              bf16* __restrict__ qb, bf16* __restrict__ kbb, bf16* __restrict__ vTb,
              float kscale) {
    const int z = blockIdx.z;
    const bf16* A  = (z == 0) ? xT : yT;
    const bf16* BT = (z == 0) ? WqT : (z == 1) ? WkT : WvT;
    const float* bias = (z == 0) ? bq : (z == 1) ? bk : bv;

    const int tid = threadIdx.x;
    const int w = tid >> 6, l = tid & 63;
    const int l15 = l & 15, lg = l >> 4;
    const int m0 = blockIdx.x * 64 + (w >> 1) * 32;
    const int n0 = blockIdx.y * 64 + (w & 1) * 32;

    f32x4 acc[2][2] = {};
    const bf16* a0 = &A[(size_t)(m0 + l15) * CCH + lg * 8];
    const bf16* b0 = &BT[(size_t)(n0 + l15) * CCH + lg * 8];

    for (int k0 = 0; k0 < CCH; k0 += 32) {
        bf16x8 a[2], b[2];
        a[0] = *reinterpret_cast<const bf16x8*>(a0 + k0);
        a[1] = *reinterpret_cast<const bf16x8*>(a0 + (size_t)16 * CCH + k0);
        b[0] = *reinterpret_cast<const bf16x8*>(b0 + k0);
        b[1] = *reinterpret_cast<const bf16x8*>(b0 + (size_t)16 * CCH + k0);
        #pragma unroll
        for (int i = 0; i < 2; ++i)
            #pragma unroll
            for (int j = 0; j < 2; ++j)
                acc[i][j] = __builtin_amdgcn_mfma_f32_16x16x32_bf16(a[i], b[j], acc[i][j], 0, 0, 0);
    }

    const float sc = (z == 1) ? kscale : 1.f;
    #pragma unroll
    for (int i = 0; i < 2; ++i) {
        #pragma unroll
        for (int j = 0; j < 2; ++j) {
            const int col = n0 + j * 16 + l15;
            const float bs = bias[col];
            #pragma unroll
            for (int r = 0; r < 4; ++r) {
                const int row = m0 + i * 16 + lg * 4 + r;
                float val = acc[i][j][r] + bs;
                if (z == 2)
                    vTb[((size_t)(col >> 5) * VROWS + (col & 31)) * SQ + row] = (bf16)val;
                else if (z == 1)
                    kbb[(size_t)row * CCH + col] = (bf16)(val * sc);
                else
                    qb[(size_t)row * CCH + col] = (bf16)val;
            }
        }
    }
}

// ---------------------------------------------------------------------------
// Fused attention-merge + Wo projection + residual + LN1 (4 waves).
// Block = 16 rows.  Stage 0: softmax denominators from Lp.  Stage 1: each
// thread owns one channel column, merges the NSPLIT Op partials for the
// block's 16 rows, normalizes, writes the bf16 A-tile to LDS [16][264]
// (rows 16B-aligned).  Stage 2: r15's proven row-panel Wo GEMM + LN1
// reading A-fragments from LDS.  Replaces attn_merge3 + the atb round-trip.
// ---------------------------------------------------------------------------
__global__ __launch_bounds__(256)
void wo_ln1m(const bf16* __restrict__ Op, const float* __restrict__ Lp,
             const bf16* __restrict__ WoT, const float* __restrict__ bo,
             const bf16* __restrict__ qb, const float* __restrict__ g,
             const float* __restrict__ beta, bf16* __restrict__ ln1b) {
    const int tid = threadIdx.x;
    const int mr = blockIdx.x * 16;

    __shared__ float sInvS[8][16];
    __shared__ __align__(16) bf16 Am[16][264];

    // stage 0: denominators (threads 0..127: one (head, row) each)
    if (tid < 128) {
        const int h = tid >> 4, qq = tid & 15;
        float L = 0.f;
        #pragma unroll
        for (int sp = 0; sp < NSPLIT; ++sp)
            L += Lp[((size_t)(sp * NH + h)) * SQ + mr + qq];
        sInvS[h][qq] = 1.0f / L;
    }

    // stage 1: merge the split partials for this block's 16 rows
    {
        const int c = tid, h = c >> 5, d = c & 31;
        float acc16[16] = {};
        #pragma unroll
        for (int sp = 0; sp < NSPLIT; ++sp) {
            const bf16* src = &Op[((size_t)((sp * NH + h) * HD + d)) * SQ + mr];
            bf16x8 v0 = *reinterpret_cast<const bf16x8*>(src);
            bf16x8 v1 = *reinterpret_cast<const bf16x8*>(src + 8);
            #pragma unroll
            for (int j = 0; j < 8; ++j) {
                acc16[j]     += (float)v0[j];
                acc16[8 + j] += (float)v1[j];
            }
        }
        __syncthreads();   // sInvS ready
        #pragma unroll
        for (int q = 0; q < 16; ++q)
            Am[q][c] = (bf16)(acc16[q] * sInvS[h][q]);
    }
    __syncthreads();

    // stage 2: Wo GEMM + residual + LN1 (A from LDS)
    const int w = tid >> 6, l = tid & 63;
    const int l15 = l & 15, lg = l >> 4;
    const int n0 = w * 64;

    f32x4 acc[4] = {};
    const bf16* b0 = &WoT[(size_t)(n0 + l15) * CCH + lg * 8];
    #pragma unroll
    for (int k0 = 0; k0 < CCH; k0 += 32) {
        bf16x8 a = *reinterpret_cast<const bf16x8*>(&Am[l15][lg * 8 + k0]);
        #pragma unroll
        for (int j = 0; j < 4; ++j) {
            bf16x8 b = *reinterpret_cast<const bf16x8*>(b0 + (size_t)j * 16 * CCH + k0);
            acc[j] = __builtin_amdgcn_mfma_f32_16x16x32_bf16(a, b, acc[j], 0, 0, 0);
        }
    }

    float val[4][4];
    float rsum[4] = {0.f, 0.f, 0.f, 0.f}, rsq[4] = {0.f, 0.f, 0.f, 0.f};
    #pragma unroll
    for (int j = 0; j < 4; ++j) {
        const int col = n0 + j * 16 + l15;
        const float bs = bo[col];
        #pragma unroll
        for (int r = 0; r < 4; ++r) {
            const int row = mr + lg * 4 + r;
            float v = acc[j][r] + bs + (float)qb[(size_t)row * CCH + col];
            val[j][r] = v;
            rsum[r] += v;
            rsq[r] += v * v;
        }
    }
    #pragma unroll
    for (int r = 0; r < 4; ++r) {
        #pragma unroll
        for (int off = 1; off < 16; off <<= 1) {
            rsum[r] += __shfl_xor(rsum[r], off);
            rsq[r]  += __shfl_xor(rsq[r], off);
        }
    }
    __shared__ float ssum[4][16], ssq[4][16];
    if (l15 == 0) {
        #pragma unroll
        for (int r = 0; r < 4; ++r) {
            ssum[w][lg * 4 + r] = rsum[r];
            ssq[w][lg * 4 + r]  = rsq[r];
        }
    }
    __syncthreads();
    float mu_[4], rs_[4];
    #pragma unroll
    for (int r = 0; r < 4; ++r) {
        const int row = lg * 4 + r;
        float s = (ssum[0][row] + ssum[1][row]) + (ssum[2][row] + ssum[3][row]);
        float q = (ssq[0][row] + ssq[1][row]) + (ssq[2][row] + ssq[3][row]);
        float mu = s * (1.0f / CCH);
        float var = q * (1.0f / CCH) - mu * mu;
        mu_[r] = mu;
        rs_[r] = rsqrtf(var + LN_EPS);
    }
    #pragma unroll
    for (int j = 0; j < 4; ++j) {
        const int col = n0 + j * 16 + l15;
        const float gg = g[col], bb = beta[col];
        #pragma unroll
        for (int r = 0; r < 4; ++r) {
            const int row = mr + lg * 4 + r;
            ln1b[(size_t)row * CCH + col] = (bf16)((val[j][r] - mu_[r]) * rs_[r] * gg + bb);
        }
    }
}

// ---------------------------------------------------------------------------
// Fused FFN2 + residual(bf16) + LN2 + output transpose, row-panel (4 waves).
// ---------------------------------------------------------------------------
__global__ __launch_bounds__(256)
void ffn2_ln2_t(const bf16* __restrict__ h1, const bf16* __restrict__ W2T,
                const float* __restrict__ bf2, const bf16* __restrict__ ln1b,
                const float* __restrict__ g, const float* __restrict__ beta,
                float* __restrict__ out) {
    const int tid = threadIdx.x;
    const int w = tid >> 6, l = tid & 63;
    const int l15 = l & 15, lg = l >> 4;
    const int mr = blockIdx.x * 16;
    const int n0 = w * 64;

    f32x4 acc[4] = {};
    const bf16* a0 = &h1[(size_t)(mr + l15) * 1024 + lg * 8];
    const bf16* b0 = &W2T[(size_t)(n0 + l15) * 1024 + lg * 8];
    for (int k0 = 0; k0 < 1024; k0 += 32) {
        bf16x8 a = *reinterpret_cast<const bf16x8*>(a0 + k0);
        #pragma unroll
        for (int j = 0; j < 4; ++j) {
            bf16x8 b = *reinterpret_cast<const bf16x8*>(b0 + (size_t)j * 16 * 1024 + k0);
            acc[j] = __builtin_amdgcn_mfma_f32_16x16x32_bf16(a, b, acc[j], 0, 0, 0);
        }
    }

    float val[4][4];
    float rsum[4] = {0.f, 0.f, 0.f, 0.f}, rsq[4] = {0.f, 0.f, 0.f, 0.f};
    #pragma unroll
    for (int j = 0; j < 4; ++j) {
        const int col = n0 + j * 16 + l15;
        const float bs = bf2[col];
        #pragma unroll
        for (int r = 0; r < 4; ++r) {
            const int row = mr + lg * 4 + r;
            float v = acc[j][r] + bs + (float)ln1b[(size_t)row * CCH + col];
            val[j][r] = v;
            rsum[r] += v;
            rsq[r] += v * v;
        }
    }
    #pragma unroll
    for (int r = 0; r < 4; ++r) {
        #pragma unroll
        for (int off = 1; off < 16; off <<= 1) {
            rsum[r] += __shfl_xor(rsum[r], off);
            rsq[r]  += __shfl_xor(rsq[r], off);
        }
    }
    __shared__ float ssum[4][16], ssq[4][16];
    if (l15 == 0) {
        #pragma unroll
        for (int r = 0; r < 4; ++r) {
            ssum[w][lg * 4 + r] = rsum[r];
            ssq[w][lg * 4 + r]  = rsq[r];
        }
    }
    __syncthreads();
    float mu_[4], rs_[4];
    #pragma unroll
    for (int r = 0; r < 4; ++r) {
        const int row = lg * 4 + r;
        float s = (ssum[0][row] + ssum[1][row]) + (ssum[2][row] + ssum[3][row]);
        float q = (ssq[0][row] + ssq[1][row]) + (ssq[2][row] + ssq[3][row]);
        float mu = s * (1.0f / CCH);
        float var = q * (1.0f / CCH) - mu * mu;
        mu_[r] = mu;
        rs_[r] = rsqrtf(var + LN_EPS);
    }

    __shared__ float tile[256][17];
    #pragma unroll
    for (int j = 0; j < 4; ++j) {
        const int col = n0 + j * 16 + l15;
        const float gg = g[col], bb = beta[col];
        #pragma unroll
        for (int r = 0; r < 4; ++r)
            tile[col][lg * 4 + r] = (val[j][r] - mu_[r]) * rs_[r] * gg + bb;
    }
    __syncthreads();
    const int c = tid;
    float* orow = &out[(size_t)c * SQ + mr];
    #pragma unroll
    for (int q4 = 0; q4 < 4; ++q4) {
        float4 o4 = {tile[c][q4 * 4], tile[c][q4 * 4 + 1],
                     tile[c][q4 * 4 + 2], tile[c][q4 * 4 + 3]};
        *reinterpret_cast<float4*>(orow + q4 * 4) = o4;
    }
}

// ---------------------------------------------------------------------------
// MFMA flash attention v11 (r15 exact): quad-Q, swapped QK^T, no-max softmax,
// LDS P relayout, K=32 PV, MFMA row-sum via ones-row, raw v_exp_f32.
// ---------------------------------------------------------------------------
__global__ __launch_bounds__(256)
void flash_attn11(const bf16* __restrict__ qb, const bf16* __restrict__ kb,
                  const bf16* __restrict__ vT, bf16* __restrict__ Op,
                  float* __restrict__ Lp) {
    const int fid = blockIdx.x + 16 * (blockIdx.y + NH * blockIdx.z);
    const int nid = (fid & 7) * 64 + (fid >> 3);
    const int q0 = (nid & 15) * 256;
    const int h  = (nid >> 4) & 7;
    const int sp = nid >> 7;

    const int tid = threadIdx.x;
    const int w = tid >> 6, l = tid & 63;
    const int l15 = l & 15, lg = l >> 4;

    __shared__ unsigned int Sb[4][2][8][72];   // [wave][parity][slot][lane] 18KB

    bf16x8 aq[4];
    #pragma unroll
    for (int su = 0; su < 4; ++su)
        aq[su] = *reinterpret_cast<const bf16x8*>(
            &qb[(size_t)(q0 + su * 64 + w * 16 + l15) * CCH + h * HD + lg * 8]);

    f32x4 o[4][2] = {};
    f32x4 o2[4] = {};   // row-sum accumulators (ones-row MFMA)

    const bf16* kfrag = &kb[(size_t)l15 * CCH + h * HD + lg * 8];
    const bf16* vfrag = &vT[((size_t)h * VROWS + l15) * SQ + lg * 8];

    const int kt0 = sp * (SQ / NSPLIT / 64);
    const int kt1 = kt0 + (SQ / NSPLIT / 64);

    for (int kt = kt0; kt < kt1; ++kt) {
        const int kb0 = kt * 64;

        bf16x8 kf[4], vf[3][2];
        #pragma unroll
        for (int t = 0; t < 4; ++t)
            kf[t] = *reinterpret_cast<const bf16x8*>(kfrag + (size_t)(kb0 + t * 16) * CCH);
        #pragma unroll
        for (int dh = 0; dh < 3; ++dh)
            #pragma unroll
            for (int kh = 0; kh < 2; ++kh)
                vf[dh][kh] = *reinterpret_cast<const bf16x8*>(
                    vfrag + (size_t)dh * 16 * SQ + kb0 + kh * 32);

        #pragma unroll
        for (int su = 0; su < 4; ++su) {
            const int par = su & 1;
            f32x4 s[4];
            #pragma unroll
            for (int t = 0; t < 4; ++t)
                s[t] = __builtin_amdgcn_mfma_f32_16x16x32_bf16(
                    kf[t], aq[su], (f32x4){0.f, 0.f, 0.f, 0.f}, 0, 0, 0);

            #pragma unroll
            for (int t = 0; t < 4; ++t) {
                unsigned int u0 = __builtin_bit_cast(unsigned int, fast_exp2(s[t][0]));
                unsigned int u1 = __builtin_bit_cast(unsigned int, fast_exp2(s[t][1]));
                unsigned int u2 = __builtin_bit_cast(unsigned int, fast_exp2(s[t][2]));
                unsigned int u3 = __builtin_bit_cast(unsigned int, fast_exp2(s[t][3]));
                Sb[w][par][t * 2 + 0][l] = __builtin_amdgcn_perm(u1, u0, 0x07060302u);
                Sb[w][par][t * 2 + 1][l] = __builtin_amdgcn_perm(u3, u2, 0x07060302u);
            }

            #pragma unroll
            for (int kh = 0; kh < 2; ++kh) {
                const int sbase = kh * 4 + (lg >> 1) * 2;
                const int i0 = l15 + 16 * ((lg & 1) * 2);
                const int i1 = i0 + 16;
                union { unsigned int u[4]; bf16x8 v; } pb;
                pb.u[0] = Sb[w][par][sbase + 0][i0];
                pb.u[1] = Sb[w][par][sbase + 1][i0];
                pb.u[2] = Sb[w][par][sbase + 0][i1];
                pb.u[3] = Sb[w][par][sbase + 1][i1];
                #pragma unroll
                for (int dh = 0; dh < 2; ++dh)
                    o[su][dh] = __builtin_amdgcn_mfma_f32_16x16x32_bf16(
                        vf[dh][kh], pb.v, o[su][dh], 0, 0, 0);
                o2[su] = __builtin_amdgcn_mfma_f32_16x16x32_bf16(
                    vf[2][kh], pb.v, o2[su], 0, 0, 0);
            }
        }
    }

    const size_t obase = ((size_t)sp * NH + h) * HD;
    #pragma unroll
    for (int su = 0; su < 4; ++su) {
        const int qrow = q0 + su * 64 + w * 16 + l15;
        #pragma unroll
        for (int dh = 0; dh < 2; ++dh)
            #pragma unroll
            for (int r = 0; r < 4; ++r)
                Op[(obase + dh * 16 + lg * 4 + r) * SQ + qrow] = (bf16)o[su][dh][r];
        if (lg == 0)
            Lp[((size_t)sp * NH + h) * SQ + qrow] = o2[su][0];
    }
}

// ---------------------------------------------------------------------------
extern "C" void kernel_launch(void* const* d_in, const int* in_sizes, int n_in,
                              void* d_out, int out_size, void* d_ws, size_t ws_size,
                              hipStream_t stream) {
    const float* lidar = (const float*)d_in[0];
    const float* image = (const float*)d_in[1];
    const float* Wq  = (const float*)d_in[2];
    const float* bq  = (const float*)d_in[3];
    const float* Wk  = (const float*)d_in[4];
    const float* bk  = (const float*)d_in[5];
    const float* Wv  = (const float*)d_in[6];
    const float* bv  = (const float*)d_in[7];
    const float* Wo  = (const float*)d_in[8];
    const float* bo  = (const float*)d_in[9];
    const float* g1  = (const float*)d_in[10];
    const float* b1  = (const float*)d_in[11];
    const float* W1  = (const float*)d_in[12];
    const float* bf1 = (const float*)d_in[13];
    const float* W2  = (const float*)d_in[14];
    const float* bf2 = (const float*)d_in[15];
    const float* g2  = (const float*)d_in[16];
    const float* b2  = (const float*)d_in[17];
    float* out = (float*)d_out;

    // workspace layout (aliased; peak 17.5 MB).  Lp (512K) in d_out until wo_ln1m.
    char* ws = (char*)d_ws;
    const size_t KB = 1024;
    bf16* W2T = (bf16*)(ws + 0);                 // [0,512K)     live -> ffn2_ln2_t
    bf16* W1T = (bf16*)(ws + 512 * KB);          // [512K,1M)    live -> ffn1
    bf16* WoT = (bf16*)(ws + 1024 * KB);         // [1,1.125M)   live -> wo_ln1m
    bf16* WqT = (bf16*)(ws + 1152 * KB);         // dead after qkv
    bf16* WkT = (bf16*)(ws + 1280 * KB);
    bf16* WvT = (bf16*)(ws + 1408 * KB);         // ends 1.5M
    bf16* qb  = (bf16*)(ws + 1536 * KB);         // [1.5,3.5M)   live -> wo_ln1m
    bf16* kbb = (bf16*)(ws + 3584 * KB);         // [3.5,5.5M)   dead after flash
    bf16* vTb = (bf16*)(ws + 5632 * KB);         // [5.5,8.5M)   padded; dead after flash
    bf16* xT  = (bf16*)(ws + 8704 * KB);         // [8.5,10.5M)  dead after qkv
    bf16* yT  = (bf16*)(ws + 10752 * KB);        // [10.5,12.5M) dead after qkv
    bf16* Op  = (bf16*)(ws + 8704 * KB);         // [8.5,16.5M)  overlays xT/yT; live -> wo_ln1m
    float* Lp = (float*)d_out;                   // 512K scratch in d_out
    bf16* ln1b = (bf16*)(ws + 5632 * KB);        // [5.5,7.5M)   reuses vTb; live -> ffn2
    bf16* h1  = (bf16*)(ws + 9728 * KB);         // [9.5,17.5M)  written after Op consumed

    // 1/sqrt(32) * log2(e) folded into K -> scores already in log2 domain
    const float qscale = 0.17677669529663687f * 1.4426950408889634f;
    dim3 blk(256);

    // all layout conversions in one launch
    cvt_all<<<dim3(2880), blk, 0, stream>>>(lidar, image, xT, yT,
                                            Wq, Wk, Wv, Wo, W1, W2,
                                            WqT, WkT, WvT, WoT, W1T, W2T, vTb);
    // fused QKV projections
    qkv_gemm<<<dim3(64, 4, 3), blk, 0, stream>>>(xT, yT, WqT, WkT, WvT,
                                                 bq, bk, bv, qb, kbb, vTb, qscale);
    // attention (split-KV x4, swapped-operand, no-max, MFMA row-sum, v_exp)
    flash_attn11<<<dim3(16, NH, NSPLIT), blk, 0, stream>>>(qb, kbb, vTb, Op, Lp);
    // fused merge + Wo projection + residual + LN1
    wo_ln1m<<<dim3(SQ / 16), blk, 0, stream>>>(Op, Lp, WoT, bo, qb, g1, b1, ln1b);
    // FFN1
    gemm_mfma<256, 2, true><<<dim3(64, 16), blk, 0, stream>>>(ln1b, W1T, bf1, nullptr, h1, 1024);
    // fused FFN2 + residual(bf16) + LN2 + transpose
    ffn2_ln2_t<<<dim3(SQ / 16), blk, 0, stream>>>(h1, W2T, bf2, ln1b, g2, b2, out);
}